// Round 1
// 765.859 us; speedup vs baseline: 1.0422x; 1.0422x over previous
//
#include <hip/hip_runtime.h>
#include <cstddef>

// Problem constants (fixed by the reference).
#define N_NODES 10000
#define F_DIM   256
#define O2_DIM  256   // 2*O
#define O_DIM   128
#define L_DIM   64
#define E_EDGES 320000
#define PAD_N   10112  // 79 * 128, padded row count for the MFMA adj GEMM

// Output layout (flat, fp32): z | adj | feat | kl
#define Z_OFF    ((size_t)0)
#define ADJ_OFF  ((size_t)N_NODES * L_DIM)                       // 640000
#define FEAT_OFF (ADJ_OFF + (size_t)N_NODES * N_NODES)           // 100640000
#define KL_OFF   (FEAT_OFF + (size_t)N_NODES * F_DIM)            // 103200000

typedef __attribute__((ext_vector_type(8))) short short8;   // 8 bf16 (4 VGPRs)
typedef __attribute__((ext_vector_type(16))) float f32x16;  // MFMA 32x32 acc

// ---------------------------------------------------------------------------
// Generic 64x64-tile fp32 GEMM: C = A[MxK] @ B[KxN] (+bias) (+relu)
// Requirements: K % 16 == 0, N % 64 == 0. M arbitrary (guarded).
// Block: 256 threads, each computes 4x4 outputs. BK = 16.
// ---------------------------------------------------------------------------
template <bool BIAS, bool RELU>
__global__ __launch_bounds__(256) void gemm64(const float* __restrict__ A,
                                              const float* __restrict__ B,
                                              const float* __restrict__ bias,
                                              float* __restrict__ C,
                                              int M, int Nc, int K) {
  __shared__ float As[16][68];   // k-major, +4 pad keeps 16B row alignment
  __shared__ float Bs[16][64];

  const int tid = threadIdx.x;
  const int tx = tid & 15;       // n direction
  const int ty = tid >> 4;       // m direction
  const int bm0 = blockIdx.y * 64;
  const int bn0 = blockIdx.x * 64;

  float acc[4][4] = {};

  for (int k0 = 0; k0 < K; k0 += 16) {
    // Stage A: 64 rows x 16 k, one float4 per thread, scatter to k-major.
    {
      int row = tid >> 2;
      int kc  = (tid & 3) << 2;
      int gr  = bm0 + row;
      float4 a = make_float4(0.f, 0.f, 0.f, 0.f);
      if (gr < M) a = *(const float4*)(A + (size_t)gr * K + k0 + kc);
      As[kc + 0][row] = a.x;
      As[kc + 1][row] = a.y;
      As[kc + 2][row] = a.z;
      As[kc + 3][row] = a.w;
    }
    // Stage B: 16 k x 64 n, direct float4.
    {
      int kr = tid >> 4;
      int nc = (tid & 15) << 2;
      *(float4*)&Bs[kr][nc] =
          *(const float4*)(B + (size_t)(k0 + kr) * Nc + bn0 + nc);
    }
    __syncthreads();

#pragma unroll
    for (int kk = 0; kk < 16; ++kk) {
      float4 av = *(const float4*)&As[kk][ty << 2];
      float4 bv = *(const float4*)&Bs[kk][tx << 2];
      float am[4] = {av.x, av.y, av.z, av.w};
      float bn[4] = {bv.x, bv.y, bv.z, bv.w};
#pragma unroll
      for (int i = 0; i < 4; ++i)
#pragma unroll
        for (int j = 0; j < 4; ++j)
          acc[i][j] = fmaf(am[i], bn[j], acc[i][j]);
    }
    __syncthreads();
  }

  float4 bb = make_float4(0.f, 0.f, 0.f, 0.f);
  if (BIAS) bb = *(const float4*)(bias + bn0 + (tx << 2));

#pragma unroll
  for (int i = 0; i < 4; ++i) {
    int gr = bm0 + (ty << 2) + i;
    if (gr >= M) continue;
    float4 v;
    v.x = acc[i][0] + bb.x;
    v.y = acc[i][1] + bb.y;
    v.z = acc[i][2] + bb.z;
    v.w = acc[i][3] + bb.w;
    if (RELU) {
      v.x = fmaxf(v.x, 0.f);
      v.y = fmaxf(v.y, 0.f);
      v.z = fmaxf(v.z, 0.f);
      v.w = fmaxf(v.w, 0.f);
    }
    *(float4*)(C + (size_t)gr * Nc + bn0 + (tx << 2)) = v;
  }
}

// ---------------------------------------------------------------------------
// Split z [N x 64] fp32 into bf16 hi/lo pair (RNE both stages), rows padded
// to PAD_N with zeros so the adj MFMA kernel needs no load guards.
// ---------------------------------------------------------------------------
__global__ __launch_bounds__(256) void split_bf16(const float* __restrict__ z,
                                                  ushort* __restrict__ zhi,
                                                  ushort* __restrict__ zlo) {
  size_t base = ((size_t)blockIdx.x * 256 + threadIdx.x) * 4;
  if (base >= (size_t)PAD_N * L_DIM) return;
  int row = (int)(base >> 6);
  float4 v = make_float4(0.f, 0.f, 0.f, 0.f);
  if (row < N_NODES) v = *(const float4*)(z + base);
  float vv[4] = {v.x, v.y, v.z, v.w};
  ushort h[4], l[4];
#pragma unroll
  for (int j = 0; j < 4; ++j) {
    float x = vv[j];
    unsigned xb = __float_as_uint(x);
    unsigned hb = (xb + 0x7fffu + ((xb >> 16) & 1u)) & 0xffff0000u;  // RNE
    float hf = __uint_as_float(hb);
    float lf = x - hf;
    unsigned lb2 = __float_as_uint(lf);
    unsigned lb = (lb2 + 0x7fffu + ((lb2 >> 16) & 1u)) >> 16;        // RNE
    h[j] = (ushort)(hb >> 16);
    l[j] = (ushort)lb;
  }
  *(ushort4*)(zhi + base) = make_ushort4(h[0], h[1], h[2], h[3]);
  *(ushort4*)(zlo + base) = make_ushort4(l[0], l[1], l[2], l[3]);
}

// ---------------------------------------------------------------------------
// Adjacency GEMM via MFMA: C = Z @ Z^T with Z split into bf16 hi+lo,
// C = hi*hi^T + hi*lo^T + lo*hi^T (the lo*lo term is ~2^-18 relative: dropped).
// Block 256 threads = 4 waves in a 2x2 grid; each wave owns a 64x64 quadrant
// of a 128x128 output tile = 2x2 mfma_f32_32x32x16_bf16 fragments.
// No LDS: zhi/zlo are 1.3 MB each -> fully L2-resident; fragments load
// straight from global. Both operands come from the same matrix, so A- and
// B-fragments use the identical per-lane pattern (row = lane&31,
// k = ks*16 + 8*(lane>>5) + j), making the k-packing self-consistent.
// ---------------------------------------------------------------------------
__global__ __launch_bounds__(256) void adj_mfma(const ushort* __restrict__ zhi,
                                                const ushort* __restrict__ zlo,
                                                float* __restrict__ C) {
  const int tid = threadIdx.x;
  const int lane = tid & 63;
  const int w = tid >> 6;          // wave 0..3
  const int wr = w >> 1;
  const int wc = w & 1;
  const int bm0 = blockIdx.y * 128 + wr * 64;
  const int bn0 = blockIdx.x * 128 + wc * 64;
  const int rlane = lane & 31;
  const int khalf = (lane >> 5) * 8;   // 0 or 8

  f32x16 acc[2][2];
#pragma unroll
  for (int i = 0; i < 2; ++i)
#pragma unroll
    for (int j = 0; j < 2; ++j)
#pragma unroll
      for (int q = 0; q < 16; ++q) acc[i][j][q] = 0.f;

  const size_t arow0 = (size_t)(bm0 + rlane) * L_DIM;
  const size_t arow1 = (size_t)(bm0 + 32 + rlane) * L_DIM;
  const size_t brow0 = (size_t)(bn0 + rlane) * L_DIM;
  const size_t brow1 = (size_t)(bn0 + 32 + rlane) * L_DIM;

#pragma unroll
  for (int ks = 0; ks < 4; ++ks) {
    const int ko = ks * 16 + khalf;
    short8 ah0 = *(const short8*)(zhi + arow0 + ko);
    short8 ah1 = *(const short8*)(zhi + arow1 + ko);
    short8 bh0 = *(const short8*)(zhi + brow0 + ko);
    short8 bh1 = *(const short8*)(zhi + brow1 + ko);
    short8 al0 = *(const short8*)(zlo + arow0 + ko);
    short8 al1 = *(const short8*)(zlo + arow1 + ko);
    short8 bl0 = *(const short8*)(zlo + brow0 + ko);
    short8 bl1 = *(const short8*)(zlo + brow1 + ko);

    // hi * hi
    acc[0][0] = __builtin_amdgcn_mfma_f32_32x32x16_bf16(ah0, bh0, acc[0][0], 0, 0, 0);
    acc[0][1] = __builtin_amdgcn_mfma_f32_32x32x16_bf16(ah0, bh1, acc[0][1], 0, 0, 0);
    acc[1][0] = __builtin_amdgcn_mfma_f32_32x32x16_bf16(ah1, bh0, acc[1][0], 0, 0, 0);
    acc[1][1] = __builtin_amdgcn_mfma_f32_32x32x16_bf16(ah1, bh1, acc[1][1], 0, 0, 0);
    // hi * lo
    acc[0][0] = __builtin_amdgcn_mfma_f32_32x32x16_bf16(ah0, bl0, acc[0][0], 0, 0, 0);
    acc[0][1] = __builtin_amdgcn_mfma_f32_32x32x16_bf16(ah0, bl1, acc[0][1], 0, 0, 0);
    acc[1][0] = __builtin_amdgcn_mfma_f32_32x32x16_bf16(ah1, bl0, acc[1][0], 0, 0, 0);
    acc[1][1] = __builtin_amdgcn_mfma_f32_32x32x16_bf16(ah1, bl1, acc[1][1], 0, 0, 0);
    // lo * hi
    acc[0][0] = __builtin_amdgcn_mfma_f32_32x32x16_bf16(al0, bh0, acc[0][0], 0, 0, 0);
    acc[0][1] = __builtin_amdgcn_mfma_f32_32x32x16_bf16(al0, bh1, acc[0][1], 0, 0, 0);
    acc[1][0] = __builtin_amdgcn_mfma_f32_32x32x16_bf16(al1, bh0, acc[1][0], 0, 0, 0);
    acc[1][1] = __builtin_amdgcn_mfma_f32_32x32x16_bf16(al1, bh1, acc[1][1], 0, 0, 0);
  }

  // C/D layout (measured, m74/m101): col = lane&31,
  // row = (reg&3) + 8*(reg>>2) + 4*(lane>>5).
#pragma unroll
  for (int ti = 0; ti < 2; ++ti) {
    const int rb = bm0 + ti * 32 + 4 * (lane >> 5);
#pragma unroll
    for (int tj = 0; tj < 2; ++tj) {
      const int col = bn0 + tj * 32 + rlane;
      if (col >= N_NODES) continue;
#pragma unroll
      for (int reg = 0; reg < 16; ++reg) {
        const int r = rb + (reg & 3) + 8 * (reg >> 2);
        if (r < N_NODES) C[(size_t)r * N_NODES + col] = acc[ti][tj][reg];
      }
    }
  }
}

// ---------------------------------------------------------------------------
// CSR build: histogram of dst, exclusive scan, cursor-based fill.
// CSR arrays live in the adj output region (written long before adj_mfma).
// ---------------------------------------------------------------------------
__global__ __launch_bounds__(256) void hist_kernel(const int* __restrict__ dst,
                                                   int* __restrict__ deg) {
  int e = blockIdx.x * blockDim.x + threadIdx.x;
  if (e < E_EDGES) atomicAdd(&deg[dst[e]], 1);
}

// Single-block exclusive scan over N_NODES degree counts.
// Writes row_start[0..N] and cursor[0..N-1] (= row_start copy).
__global__ __launch_bounds__(256) void scan_kernel(const int* __restrict__ deg,
                                                   int* __restrict__ row_start,
                                                   int* __restrict__ cursor) {
  constexpr int CH = (N_NODES + 255) / 256;  // 40
  const int t = threadIdx.x;
  __shared__ int ps[256];

  int base = t * CH;
  int sum = 0;
  for (int i = base; i < base + CH && i < N_NODES; ++i) sum += deg[i];
  ps[t] = sum;
  __syncthreads();
  // inclusive Hillis-Steele scan
  for (int off = 1; off < 256; off <<= 1) {
    int v = (t >= off) ? ps[t - off] : 0;
    __syncthreads();
    ps[t] += v;
    __syncthreads();
  }
  int running = ps[t] - sum;  // exclusive base for this chunk
  for (int i = base; i < base + CH && i < N_NODES; ++i) {
    row_start[i] = running;
    cursor[i] = running;
    running += deg[i];
  }
  if (t == 255) row_start[N_NODES] = ps[255];
}

__global__ __launch_bounds__(256) void fill_kernel(
    const int* __restrict__ src, const int* __restrict__ dst,
    const float* __restrict__ ew, int* __restrict__ cursor,
    int* __restrict__ csr_src, float* __restrict__ csr_w) {
  int e = blockIdx.x * blockDim.x + threadIdx.x;
  if (e >= E_EDGES) return;
  int d = dst[e];
  int pos = atomicAdd(&cursor[d], 1);
  csr_src[pos] = src[e];
  csr_w[pos] = ew[e];
}

// ---------------------------------------------------------------------------
// Gather-based GCN aggregation: out[n] = act( sum_{e: dst=n} w_e * H[src_e] + b )
// One wave per node; lane holds VEC = D/64 features in registers.
// Edge loop unrolled x4 so the 4 row loads issue concurrently.
// ---------------------------------------------------------------------------
template <int D, bool RELU>
__global__ __launch_bounds__(256) void gcn_gather(
    const float* __restrict__ H, const int* __restrict__ row_start,
    const int* __restrict__ csr_src, const float* __restrict__ csr_w,
    const float* __restrict__ bias, float* __restrict__ out) {
  constexpr int VEC = D / 64;  // 4 (D=256) or 2 (D=128)
  const int wid = threadIdx.x >> 6;
  const int lane = threadIdx.x & 63;
  const int n = blockIdx.x * 4 + wid;
  if (n >= N_NODES) return;

  const int beg = row_start[n];
  const int end = row_start[n + 1];

  float acc[VEC] = {};
  int i = beg;
  for (; i + 4 <= end; i += 4) {
    int ss[4];
    float ww[4];
#pragma unroll
    for (int u = 0; u < 4; ++u) {
      ss[u] = csr_src[i + u];
      ww[u] = csr_w[i + u];
    }
    float vv[4][VEC];
#pragma unroll
    for (int u = 0; u < 4; ++u) {
      const float* rp = H + (size_t)ss[u] * D + lane * VEC;
      if constexpr (VEC == 4) {
        float4 v = *(const float4*)rp;
        vv[u][0] = v.x; vv[u][1] = v.y; vv[u][2] = v.z; vv[u][3] = v.w;
      } else {
        float2 v = *(const float2*)rp;
        vv[u][0] = v.x; vv[u][1] = v.y;
      }
    }
#pragma unroll
    for (int u = 0; u < 4; ++u)
#pragma unroll
      for (int c = 0; c < VEC; ++c) acc[c] = fmaf(vv[u][c], ww[u], acc[c]);
  }
  for (; i < end; ++i) {
    int s = csr_src[i];
    float w = csr_w[i];
    const float* rp = H + (size_t)s * D + lane * VEC;
    if constexpr (VEC == 4) {
      float4 v = *(const float4*)rp;
      acc[0] = fmaf(v.x, w, acc[0]);
      acc[1] = fmaf(v.y, w, acc[1]);
      acc[2] = fmaf(v.z, w, acc[2]);
      acc[3] = fmaf(v.w, w, acc[3]);
    } else {
      float2 v = *(const float2*)rp;
      acc[0] = fmaf(v.x, w, acc[0]);
      acc[1] = fmaf(v.y, w, acc[1]);
    }
  }

  float* op = out + (size_t)n * D + lane * VEC;
  if constexpr (VEC == 4) {
    float4 b = *(const float4*)(bias + lane * 4);
    float4 r = make_float4(acc[0] + b.x, acc[1] + b.y, acc[2] + b.z,
                           acc[3] + b.w);
    if (RELU) {
      r.x = fmaxf(r.x, 0.f); r.y = fmaxf(r.y, 0.f);
      r.z = fmaxf(r.z, 0.f); r.w = fmaxf(r.w, 0.f);
    }
    *(float4*)op = r;
  } else {
    float2 b = *(const float2*)(bias + lane * 2);
    float2 r = make_float2(acc[0] + b.x, acc[1] + b.y);
    if (RELU) {
      r.x = fmaxf(r.x, 0.f); r.y = fmaxf(r.y, 0.f);
    }
    *(float2*)op = r;
  }
}

// ---------------------------------------------------------------------------
// Sampler + KL: z = clip(m,±10) + exp(0.5*clip(v,±10))*eps;
// kl += -0.5 * (1 + log(max(v,1e-7)) - m^2 - max(v,1e-7))
// ---------------------------------------------------------------------------
__global__ __launch_bounds__(256) void sampler(const float* __restrict__ mean,
                                               const float* __restrict__ var,
                                               const float* __restrict__ eps,
                                               float* __restrict__ z,
                                               float* __restrict__ kl) {
  int i = blockIdx.x * blockDim.x + threadIdx.x;
  float kls = 0.f;
  if (i < N_NODES * L_DIM) {
    float m = mean[i];
    float v = var[i];
    float vp = fmaxf(v, 1e-7f);
    kls = 1.0f + logf(vp) - m * m - vp;
    float mc = fminf(fmaxf(m, -10.f), 10.f);
    float vc = fminf(fmaxf(v, -10.f), 10.f);
    z[i] = mc + expf(0.5f * vc) * eps[i];
  }
#pragma unroll
  for (int off = 32; off > 0; off >>= 1) kls += __shfl_down(kls, off, 64);
  __shared__ float wsum[4];
  if ((threadIdx.x & 63) == 0) wsum[threadIdx.x >> 6] = kls;
  __syncthreads();
  if (threadIdx.x == 0) {
    float s = wsum[0] + wsum[1] + wsum[2] + wsum[3];
    atomicAdd(kl, -0.5f * s);
  }
}

// ---------------------------------------------------------------------------
extern "C" void kernel_launch(void* const* d_in, const int* in_sizes, int n_in,
                              void* d_out, int out_size, void* d_ws,
                              size_t ws_size, hipStream_t stream) {
  const float* x  = (const float*)d_in[0];
  const int*   ei = (const int*)d_in[1];
  const float* ew = (const float*)d_in[2];
  const float* W1 = (const float*)d_in[3];
  const float* b1 = (const float*)d_in[4];
  const float* W2 = (const float*)d_in[5];
  const float* b2 = (const float*)d_in[6];
  const float* Wm = (const float*)d_in[7];
  const float* bm = (const float*)d_in[8];
  const float* Wv = (const float*)d_in[9];
  const float* bv = (const float*)d_in[10];
  const float* Wd = (const float*)d_in[11];
  const float* bd = (const float*)d_in[12];
  const float* eps = (const float*)d_in[13];

  const int* srcv = ei;             // edge_index[0]
  const int* dstv = ei + E_EDGES;   // edge_index[1]

  float* out  = (float*)d_out;
  float* z    = out + Z_OFF;
  float* adj  = out + ADJ_OFF;
  float* feat = out + FEAT_OFF;
  float* kl   = out + KL_OFF;

  // Workspace: two ping-pong buffers of N*256 floats (10.24 MB each).
  float* bufA = (float*)d_ws;
  float* bufB = bufA + (size_t)N_NODES * F_DIM;

  // CSR scratch lives in the adj output region (adj is written last).
  int* deg       = (int*)adj;
  int* row_start = deg + N_NODES;          // N+1 entries
  int* cursor    = row_start + N_NODES + 1;
  int* csr_src   = cursor + N_NODES;
  float* csr_w   = (float*)(csr_src + E_EDGES);

  // --- CSR build (once, reused by both convs) ---
  hipMemsetAsync(deg, 0, N_NODES * sizeof(int), stream);
  hist_kernel<<<(E_EDGES + 255) / 256, 256, 0, stream>>>(dstv, deg);
  scan_kernel<<<1, 256, 0, stream>>>(deg, row_start, cursor);
  fill_kernel<<<(E_EDGES + 255) / 256, 256, 0, stream>>>(srcv, dstv, ew, cursor,
                                                         csr_src, csr_w);

  // 1. XW1 = x @ W1  [N, 256] -> bufA
  gemm64<false, false><<<dim3(O2_DIM / 64, (N_NODES + 63) / 64), 256, 0,
                         stream>>>(x, W1, nullptr, bufA, N_NODES, O2_DIM, F_DIM);

  // 2. h1 = relu(A_hat @ XW1 + b1) -> bufB (gather, fused bias+relu)
  gcn_gather<O2_DIM, true><<<(N_NODES + 3) / 4, 256, 0, stream>>>(
      bufA, row_start, csr_src, csr_w, b1, bufB);

  // 3. H2 = h1 @ W2  [N, 128] -> bufA
  gemm64<false, false><<<dim3(O_DIM / 64, (N_NODES + 63) / 64), 256, 0,
                         stream>>>(bufB, W2, nullptr, bufA, N_NODES, O_DIM,
                                   O2_DIM);

  // 4. h2 = A_hat @ H2 + b2 -> bufB (gather, fused bias)
  gcn_gather<O_DIM, false><<<(N_NODES + 3) / 4, 256, 0, stream>>>(
      bufA, row_start, csr_src, csr_w, b2, bufB);

  // 5. mean = h2@Wm + bm; var = h2@Wv + bv -> bufA
  float* meanb = bufA;
  float* varb  = bufA + (size_t)N_NODES * L_DIM;
  gemm64<true, false><<<dim3(1, (N_NODES + 63) / 64), 256, 0, stream>>>(
      bufB, Wm, bm, meanb, N_NODES, L_DIM, O_DIM);
  gemm64<true, false><<<dim3(1, (N_NODES + 63) / 64), 256, 0, stream>>>(
      bufB, Wv, bv, varb, N_NODES, L_DIM, O_DIM);

  // 6. kl = 0; sampler writes z and accumulates kl
  hipMemsetAsync(kl, 0, sizeof(float), stream);
  sampler<<<(N_NODES * L_DIM + 255) / 256, 256, 0, stream>>>(meanb, varb, eps,
                                                             z, kl);

  // 6.5 split z into bf16 hi/lo in bufB (h2 is dead now); rows padded to
  //     PAD_N with zeros so adj_mfma needs no load guards.
  ushort* zhi = (ushort*)bufB;
  ushort* zlo = zhi + (size_t)PAD_N * L_DIM;
  split_bf16<<<(PAD_N * L_DIM / 4 + 255) / 256, 256, 0, stream>>>(z, zhi, zlo);

  // 7. adj = z @ z^T via bf16x2-split MFMA (overwrites CSR scratch — dead)
  adj_mfma<<<dim3(PAD_N / 128, PAD_N / 128), 256, 0, stream>>>(zhi, zlo, adj);

  // 8. feat = relu(z @ Wd + bd)  [N, 256]
  gemm64<true, true><<<dim3(F_DIM / 64, (N_NODES + 63) / 64), 256, 0, stream>>>(
      z, Wd, bd, feat, N_NODES, F_DIM, L_DIM);
}

// Round 2
// 749.650 us; speedup vs baseline: 1.0647x; 1.0216x over previous
//
#include <hip/hip_runtime.h>
#include <cstddef>

// Problem constants (fixed by the reference).
#define N_NODES 10000
#define F_DIM   256
#define O2_DIM  256   // 2*O
#define O_DIM   128
#define L_DIM   64
#define E_EDGES 320000

// Output layout (flat, fp32): z | adj | feat | kl
#define Z_OFF    ((size_t)0)
#define ADJ_OFF  ((size_t)N_NODES * L_DIM)                       // 640000
#define FEAT_OFF (ADJ_OFF + (size_t)N_NODES * N_NODES)           // 100640000
#define KL_OFF   (FEAT_OFF + (size_t)N_NODES * F_DIM)            // 103200000

typedef __attribute__((ext_vector_type(8))) short short8;   // 8 bf16 (4 VGPRs)
typedef __attribute__((ext_vector_type(16))) float f32x16;  // MFMA 32x32 acc

// ---------------------------------------------------------------------------
// bf16 hi/lo split helper (RNE both stages). hi+lo reconstructs x to ~2^-24.
// ---------------------------------------------------------------------------
__device__ __forceinline__ void bsplit(float x, ushort& h, ushort& l) {
  unsigned xb = __float_as_uint(x);
  unsigned hb = (xb + 0x7fffu + ((xb >> 16) & 1u)) & 0xffff0000u;  // RNE
  h = (ushort)(hb >> 16);
  float lf = x - __uint_as_float(hb);
  unsigned lb = __float_as_uint(lf);
  l = (ushort)((lb + 0x7fffu + ((lb >> 16) & 1u)) >> 16);          // RNE
}

// ---------------------------------------------------------------------------
// Activation split: fp32 [count4*4 elements] -> bf16 hi/lo arrays.
// ---------------------------------------------------------------------------
__global__ __launch_bounds__(256) void split_act(const float* __restrict__ src,
                                                 ushort* __restrict__ hi,
                                                 ushort* __restrict__ lo,
                                                 int count4) {
  int t = blockIdx.x * 256 + threadIdx.x;
  if (t >= count4) return;
  float4 v = ((const float4*)src)[t];
  float vv[4] = {v.x, v.y, v.z, v.w};
  ushort h[4], l[4];
#pragma unroll
  for (int j = 0; j < 4; ++j) bsplit(vv[j], h[j], l[j]);
  ((ushort4*)hi)[t] = make_ushort4(h[0], h[1], h[2], h[3]);
  ((ushort4*)lo)[t] = make_ushort4(l[0], l[1], l[2], l[3]);
}

// ---------------------------------------------------------------------------
// Weight split + transpose: W [K x N] row-major -> hi/lo [N x K] row-major.
// Output-indexed so writes are coalesced; scattered reads hit L2 (tiny mats).
// ---------------------------------------------------------------------------
__global__ __launch_bounds__(256) void wsplit_t(const float* __restrict__ W,
                                                ushort* __restrict__ hi,
                                                ushort* __restrict__ lo,
                                                int K, int N) {
  int idx = blockIdx.x * 256 + threadIdx.x;
  if (idx >= K * N) return;
  int n = idx / K;
  int k = idx - n * K;
  ushort h, l;
  bsplit(W[(size_t)k * N + n], h, l);
  hi[idx] = h;
  lo[idx] = l;
}

// Stacked mean|var weights: out [128 x 128] (N x K), cols of Wm then Wv.
// Also packs the combined bias vector bmv[128] = bm | bv.
__global__ __launch_bounds__(256) void wsplit_mv(const float* __restrict__ Wm,
                                                 const float* __restrict__ Wv,
                                                 const float* __restrict__ bm,
                                                 const float* __restrict__ bv,
                                                 ushort* __restrict__ hi,
                                                 ushort* __restrict__ lo,
                                                 float* __restrict__ bmv) {
  int idx = blockIdx.x * 256 + threadIdx.x;
  if (idx >= 128 * 128) return;
  int n = idx >> 7;        // output row  (N index, 0..127)
  int k = idx & 127;       // output col  (K index, 0..127)
  float v = (n < 64) ? Wm[(size_t)k * 64 + n] : Wv[(size_t)k * 64 + (n - 64)];
  ushort h, l;
  bsplit(v, h, l);
  hi[idx] = h;
  lo[idx] = l;
  if (idx < 128) bmv[idx] = (idx < 64) ? bm[idx] : bv[idx - 64];
}

// ---------------------------------------------------------------------------
// Generic MFMA GEMM: C[MxNc] = A[MxK] @ B[KxNc] (+bias) (+relu), where both
// operands are pre-split bf16 hi/lo and B is pre-transposed to [Nc x K].
// All 4 cross products (hh+hl+lh+ll) -> ~fp32 accuracy.
// Tile 64x64, 4 waves in 2x2; each wave owns one 32x32 fragment.
// No LDS: operands are L2-resident; fragments load straight from global.
// A-row index clamped to M-1 (garbage confined to unstored C rows).
// Requires K % 16 == 0, Nc % 64 == 0.
// ---------------------------------------------------------------------------
template <bool BIAS, bool RELU>
__global__ __launch_bounds__(256) void gemm_mfma(
    const ushort* __restrict__ Ahi, const ushort* __restrict__ Alo,
    const ushort* __restrict__ Bhi, const ushort* __restrict__ Blo,
    const float* __restrict__ bias, float* __restrict__ C,
    int M, int Nc, int K) {
  const int tid = threadIdx.x;
  const int lane = tid & 63;
  const int w = tid >> 6;
  const int wr = w >> 1;
  const int wc = w & 1;
  const int bm0 = blockIdx.y * 64 + wr * 32;
  const int bn0 = blockIdx.x * 64 + wc * 32;
  const int rlane = lane & 31;
  const int khalf = (lane >> 5) * 8;

  int arow = bm0 + rlane;
  if (arow >= M) arow = M - 1;               // clamp: garbage rows unstored
  const size_t abase = (size_t)arow * K;
  const size_t bbase = (size_t)(bn0 + rlane) * K;   // always < Nc

  f32x16 acc;
#pragma unroll
  for (int q = 0; q < 16; ++q) acc[q] = 0.f;

  for (int ko = khalf; ko < K; ko += 16) {
    short8 ah = *(const short8*)(Ahi + abase + ko);
    short8 al = *(const short8*)(Alo + abase + ko);
    short8 bh = *(const short8*)(Bhi + bbase + ko);
    short8 bl = *(const short8*)(Blo + bbase + ko);
    acc = __builtin_amdgcn_mfma_f32_32x32x16_bf16(ah, bh, acc, 0, 0, 0);
    acc = __builtin_amdgcn_mfma_f32_32x32x16_bf16(ah, bl, acc, 0, 0, 0);
    acc = __builtin_amdgcn_mfma_f32_32x32x16_bf16(al, bh, acc, 0, 0, 0);
    acc = __builtin_amdgcn_mfma_f32_32x32x16_bf16(al, bl, acc, 0, 0, 0);
  }

  // C/D layout (measured, m74/m101): col = lane&31,
  // row = (reg&3) + 8*(reg>>2) + 4*(lane>>5).
  const int rbase = bm0 + 4 * (lane >> 5);
  const int col = bn0 + rlane;
  float bb = 0.f;
  if (BIAS) bb = bias[col];
#pragma unroll
  for (int reg = 0; reg < 16; ++reg) {
    int r = rbase + (reg & 3) + 8 * (reg >> 2);
    if (r < M) {
      float v = acc[reg] + bb;
      if (RELU) v = fmaxf(v, 0.f);
      C[(size_t)r * Nc + col] = v;
    }
  }
}

// ---------------------------------------------------------------------------
// Adjacency GEMM via MFMA: C = Z @ Z^T with Z split into bf16 hi+lo,
// C = hi*hi^T + hi*lo^T + lo*hi^T (lo*lo ~2^-18 relative: dropped).
// 128x128 tile, 4 waves 2x2, each wave a 64x64 quadrant (2x2 fragments).
// Rows clamped to N-1 (garbage confined to unstored rows/cols).
// ---------------------------------------------------------------------------
__global__ __launch_bounds__(256) void adj_mfma(const ushort* __restrict__ zhi,
                                                const ushort* __restrict__ zlo,
                                                float* __restrict__ C) {
  const int tid = threadIdx.x;
  const int lane = tid & 63;
  const int w = tid >> 6;          // wave 0..3
  const int wr = w >> 1;
  const int wc = w & 1;
  const int bm0 = blockIdx.y * 128 + wr * 64;
  const int bn0 = blockIdx.x * 128 + wc * 64;
  const int rlane = lane & 31;
  const int khalf = (lane >> 5) * 8;   // 0 or 8

  f32x16 acc[2][2];
#pragma unroll
  for (int i = 0; i < 2; ++i)
#pragma unroll
    for (int j = 0; j < 2; ++j)
#pragma unroll
      for (int q = 0; q < 16; ++q) acc[i][j][q] = 0.f;

  int ar0 = bm0 + rlane;        if (ar0 >= N_NODES) ar0 = N_NODES - 1;
  int ar1 = bm0 + 32 + rlane;   if (ar1 >= N_NODES) ar1 = N_NODES - 1;
  int br0 = bn0 + rlane;        if (br0 >= N_NODES) br0 = N_NODES - 1;
  int br1 = bn0 + 32 + rlane;   if (br1 >= N_NODES) br1 = N_NODES - 1;
  const size_t arow0 = (size_t)ar0 * L_DIM;
  const size_t arow1 = (size_t)ar1 * L_DIM;
  const size_t brow0 = (size_t)br0 * L_DIM;
  const size_t brow1 = (size_t)br1 * L_DIM;

#pragma unroll
  for (int ks = 0; ks < 4; ++ks) {
    const int ko = ks * 16 + khalf;
    short8 ah0 = *(const short8*)(zhi + arow0 + ko);
    short8 ah1 = *(const short8*)(zhi + arow1 + ko);
    short8 bh0 = *(const short8*)(zhi + brow0 + ko);
    short8 bh1 = *(const short8*)(zhi + brow1 + ko);
    short8 al0 = *(const short8*)(zlo + arow0 + ko);
    short8 al1 = *(const short8*)(zlo + arow1 + ko);
    short8 bl0 = *(const short8*)(zlo + brow0 + ko);
    short8 bl1 = *(const short8*)(zlo + brow1 + ko);

    // hi * hi
    acc[0][0] = __builtin_amdgcn_mfma_f32_32x32x16_bf16(ah0, bh0, acc[0][0], 0, 0, 0);
    acc[0][1] = __builtin_amdgcn_mfma_f32_32x32x16_bf16(ah0, bh1, acc[0][1], 0, 0, 0);
    acc[1][0] = __builtin_amdgcn_mfma_f32_32x32x16_bf16(ah1, bh0, acc[1][0], 0, 0, 0);
    acc[1][1] = __builtin_amdgcn_mfma_f32_32x32x16_bf16(ah1, bh1, acc[1][1], 0, 0, 0);
    // hi * lo
    acc[0][0] = __builtin_amdgcn_mfma_f32_32x32x16_bf16(ah0, bl0, acc[0][0], 0, 0, 0);
    acc[0][1] = __builtin_amdgcn_mfma_f32_32x32x16_bf16(ah0, bl1, acc[0][1], 0, 0, 0);
    acc[1][0] = __builtin_amdgcn_mfma_f32_32x32x16_bf16(ah1, bl0, acc[1][0], 0, 0, 0);
    acc[1][1] = __builtin_amdgcn_mfma_f32_32x32x16_bf16(ah1, bl1, acc[1][1], 0, 0, 0);
    // lo * hi
    acc[0][0] = __builtin_amdgcn_mfma_f32_32x32x16_bf16(al0, bh0, acc[0][0], 0, 0, 0);
    acc[0][1] = __builtin_amdgcn_mfma_f32_32x32x16_bf16(al0, bh1, acc[0][1], 0, 0, 0);
    acc[1][0] = __builtin_amdgcn_mfma_f32_32x32x16_bf16(al1, bh0, acc[1][0], 0, 0, 0);
    acc[1][1] = __builtin_amdgcn_mfma_f32_32x32x16_bf16(al1, bh1, acc[1][1], 0, 0, 0);
  }

#pragma unroll
  for (int ti = 0; ti < 2; ++ti) {
    const int rb = bm0 + ti * 32 + 4 * (lane >> 5);
#pragma unroll
    for (int tj = 0; tj < 2; ++tj) {
      const int col = bn0 + tj * 32 + rlane;
      if (col >= N_NODES) continue;
#pragma unroll
      for (int reg = 0; reg < 16; ++reg) {
        const int r = rb + (reg & 3) + 8 * (reg >> 2);
        if (r < N_NODES) C[(size_t)r * N_NODES + col] = acc[ti][tj][reg];
      }
    }
  }
}

// ---------------------------------------------------------------------------
// CSR build: histogram of dst, exclusive scan, cursor-based fill.
// CSR arrays live in the adj output region (written long before adj_mfma).
// ---------------------------------------------------------------------------
__global__ __launch_bounds__(256) void hist_kernel(const int* __restrict__ dst,
                                                   int* __restrict__ deg) {
  int e = blockIdx.x * blockDim.x + threadIdx.x;
  if (e < E_EDGES) atomicAdd(&deg[dst[e]], 1);
}

// Single-block exclusive scan over N_NODES degree counts.
__global__ __launch_bounds__(256) void scan_kernel(const int* __restrict__ deg,
                                                   int* __restrict__ row_start,
                                                   int* __restrict__ cursor) {
  constexpr int CH = (N_NODES + 255) / 256;  // 40
  const int t = threadIdx.x;
  __shared__ int ps[256];

  int base = t * CH;
  int sum = 0;
  for (int i = base; i < base + CH && i < N_NODES; ++i) sum += deg[i];
  ps[t] = sum;
  __syncthreads();
  for (int off = 1; off < 256; off <<= 1) {
    int v = (t >= off) ? ps[t - off] : 0;
    __syncthreads();
    ps[t] += v;
    __syncthreads();
  }
  int running = ps[t] - sum;
  for (int i = base; i < base + CH && i < N_NODES; ++i) {
    row_start[i] = running;
    cursor[i] = running;
    running += deg[i];
  }
  if (t == 255) row_start[N_NODES] = ps[255];
}

__global__ __launch_bounds__(256) void fill_kernel(
    const int* __restrict__ src, const int* __restrict__ dst,
    const float* __restrict__ ew, int* __restrict__ cursor,
    int* __restrict__ csr_src, float* __restrict__ csr_w) {
  int e = blockIdx.x * blockDim.x + threadIdx.x;
  if (e >= E_EDGES) return;
  int d = dst[e];
  int pos = atomicAdd(&cursor[d], 1);
  csr_src[pos] = src[e];
  csr_w[pos] = ew[e];
}

// ---------------------------------------------------------------------------
// Gather-based GCN aggregation: out[n] = act( sum_{e: dst=n} w_e * H[src_e] + b )
// One wave per node; lane holds VEC = D/64 features in registers.
// ---------------------------------------------------------------------------
template <int D, bool RELU>
__global__ __launch_bounds__(256) void gcn_gather(
    const float* __restrict__ H, const int* __restrict__ row_start,
    const int* __restrict__ csr_src, const float* __restrict__ csr_w,
    const float* __restrict__ bias, float* __restrict__ out) {
  constexpr int VEC = D / 64;  // 4 (D=256) or 2 (D=128)
  const int wid = threadIdx.x >> 6;
  const int lane = threadIdx.x & 63;
  const int n = blockIdx.x * 4 + wid;
  if (n >= N_NODES) return;

  const int beg = row_start[n];
  const int end = row_start[n + 1];

  float acc[VEC] = {};
  int i = beg;
  for (; i + 4 <= end; i += 4) {
    int ss[4];
    float ww[4];
#pragma unroll
    for (int u = 0; u < 4; ++u) {
      ss[u] = csr_src[i + u];
      ww[u] = csr_w[i + u];
    }
    float vv[4][VEC];
#pragma unroll
    for (int u = 0; u < 4; ++u) {
      const float* rp = H + (size_t)ss[u] * D + lane * VEC;
      if constexpr (VEC == 4) {
        float4 v = *(const float4*)rp;
        vv[u][0] = v.x; vv[u][1] = v.y; vv[u][2] = v.z; vv[u][3] = v.w;
      } else {
        float2 v = *(const float2*)rp;
        vv[u][0] = v.x; vv[u][1] = v.y;
      }
    }
#pragma unroll
    for (int u = 0; u < 4; ++u)
#pragma unroll
      for (int c = 0; c < VEC; ++c) acc[c] = fmaf(vv[u][c], ww[u], acc[c]);
  }
  for (; i < end; ++i) {
    int s = csr_src[i];
    float w = csr_w[i];
    const float* rp = H + (size_t)s * D + lane * VEC;
    if constexpr (VEC == 4) {
      float4 v = *(const float4*)rp;
      acc[0] = fmaf(v.x, w, acc[0]);
      acc[1] = fmaf(v.y, w, acc[1]);
      acc[2] = fmaf(v.z, w, acc[2]);
      acc[3] = fmaf(v.w, w, acc[3]);
    } else {
      float2 v = *(const float2*)rp;
      acc[0] = fmaf(v.x, w, acc[0]);
      acc[1] = fmaf(v.y, w, acc[1]);
    }
  }

  float* op = out + (size_t)n * D + lane * VEC;
  if constexpr (VEC == 4) {
    float4 b = *(const float4*)(bias + lane * 4);
    float4 r = make_float4(acc[0] + b.x, acc[1] + b.y, acc[2] + b.z,
                           acc[3] + b.w);
    if (RELU) {
      r.x = fmaxf(r.x, 0.f); r.y = fmaxf(r.y, 0.f);
      r.z = fmaxf(r.z, 0.f); r.w = fmaxf(r.w, 0.f);
    }
    *(float4*)op = r;
  } else {
    float2 b = *(const float2*)(bias + lane * 2);
    float2 r = make_float2(acc[0] + b.x, acc[1] + b.y);
    if (RELU) {
      r.x = fmaxf(r.x, 0.f); r.y = fmaxf(r.y, 0.f);
    }
    *(float2*)op = r;
  }
}

// ---------------------------------------------------------------------------
// Fused sampler + KL + z bf16-split.
// mv layout: [node][0:64]=mean, [node][64:128]=var.
// z = clip(m,±10) + exp(0.5*clip(v,±10))*eps;
// kl += -0.5 * (1 + log(max(v,1e-7)) - m^2 - max(v,1e-7))
// ---------------------------------------------------------------------------
__global__ __launch_bounds__(256) void sampler_fused(
    const float* __restrict__ mv, const float* __restrict__ eps,
    float* __restrict__ z, float* __restrict__ kl,
    ushort* __restrict__ zhi, ushort* __restrict__ zlo) {
  int t = blockIdx.x * 256 + threadIdx.x;   // one float4 of z per thread
  float kls = 0.f;
  if (t < N_NODES * L_DIM / 4) {
    int node = t >> 4;
    int jq = (t & 15) << 2;
    float4 m4 = *(const float4*)(mv + (size_t)node * 128 + jq);
    float4 v4 = *(const float4*)(mv + (size_t)node * 128 + 64 + jq);
    float4 e4 = *(const float4*)(eps + (size_t)node * 64 + jq);
    float mm[4] = {m4.x, m4.y, m4.z, m4.w};
    float vv[4] = {v4.x, v4.y, v4.z, v4.w};
    float ee[4] = {e4.x, e4.y, e4.z, e4.w};
    float zf[4];
    ushort h[4], l[4];
#pragma unroll
    for (int j = 0; j < 4; ++j) {
      float m = mm[j], v = vv[j];
      float vp = fmaxf(v, 1e-7f);
      kls += 1.0f + logf(vp) - m * m - vp;
      float mc = fminf(fmaxf(m, -10.f), 10.f);
      float vc = fminf(fmaxf(v, -10.f), 10.f);
      float zz = mc + expf(0.5f * vc) * ee[j];
      zf[j] = zz;
      bsplit(zz, h[j], l[j]);
    }
    *(float4*)(z + (size_t)node * 64 + jq) =
        make_float4(zf[0], zf[1], zf[2], zf[3]);
    *(ushort4*)(zhi + (size_t)node * 64 + jq) =
        make_ushort4(h[0], h[1], h[2], h[3]);
    *(ushort4*)(zlo + (size_t)node * 64 + jq) =
        make_ushort4(l[0], l[1], l[2], l[3]);
  }
#pragma unroll
  for (int off = 32; off > 0; off >>= 1) kls += __shfl_down(kls, off, 64);
  __shared__ float wsum[4];
  if ((threadIdx.x & 63) == 0) wsum[threadIdx.x >> 6] = kls;
  __syncthreads();
  if (threadIdx.x == 0) {
    float s = wsum[0] + wsum[1] + wsum[2] + wsum[3];
    atomicAdd(kl, -0.5f * s);
  }
}

// ---------------------------------------------------------------------------
extern "C" void kernel_launch(void* const* d_in, const int* in_sizes, int n_in,
                              void* d_out, int out_size, void* d_ws,
                              size_t ws_size, hipStream_t stream) {
  const float* x  = (const float*)d_in[0];
  const int*   ei = (const int*)d_in[1];
  const float* ew = (const float*)d_in[2];
  const float* W1 = (const float*)d_in[3];
  const float* b1 = (const float*)d_in[4];
  const float* W2 = (const float*)d_in[5];
  const float* b2 = (const float*)d_in[6];
  const float* Wm = (const float*)d_in[7];
  const float* bm = (const float*)d_in[8];
  const float* Wv = (const float*)d_in[9];
  const float* bv = (const float*)d_in[10];
  const float* Wd = (const float*)d_in[11];
  const float* bd = (const float*)d_in[12];
  const float* eps = (const float*)d_in[13];

  const int* srcv = ei;             // edge_index[0]
  const int* dstv = ei + E_EDGES;   // edge_index[1]

  float* out  = (float*)d_out;
  float* z    = out + Z_OFF;
  float* adj  = out + ADJ_OFF;
  float* feat = out + FEAT_OFF;
  float* kl   = out + KL_OFF;

  // Workspace: two ping-pong buffers of N*256 floats (10.24 MB each).
  float* bufA = (float*)d_ws;
  float* bufB = bufA + (size_t)N_NODES * F_DIM;

  // Scratch in the adj output region (adj is written last):
  // CSR arrays + transposed/split weights + combined mean|var bias.
  int* deg       = (int*)adj;
  int* row_start = deg + N_NODES;          // N+1 entries
  int* cursor    = row_start + N_NODES + 1;
  int* csr_src   = cursor + N_NODES;
  float* csr_w   = (float*)(csr_src + E_EDGES);

  ushort* W1t_hi = (ushort*)(csr_w + E_EDGES);   // [256 x 256]
  ushort* W1t_lo = W1t_hi + 256 * 256;
  ushort* W2t_hi = W1t_lo + 256 * 256;           // [128 x 256]
  ushort* W2t_lo = W2t_hi + 128 * 256;
  ushort* Wmv_hi = W2t_lo + 128 * 256;           // [128 x 128] (Wm|Wv stacked)
  ushort* Wmv_lo = Wmv_hi + 128 * 128;
  ushort* Wdt_hi = Wmv_lo + 128 * 128;           // [256 x 64]
  ushort* Wdt_lo = Wdt_hi + 256 * 64;
  float*  bmv_c  = (float*)(Wdt_lo + 256 * 64);  // [128] = bm | bv

  // --- CSR build (once, reused by both convs) ---
  hipMemsetAsync(deg, 0, N_NODES * sizeof(int), stream);
  hist_kernel<<<(E_EDGES + 255) / 256, 256, 0, stream>>>(dstv, deg);
  scan_kernel<<<1, 256, 0, stream>>>(deg, row_start, cursor);
  fill_kernel<<<(E_EDGES + 255) / 256, 256, 0, stream>>>(srcv, dstv, ew, cursor,
                                                         csr_src, csr_w);

  // --- Weight splits (transposed to [N x K]) ---
  wsplit_t<<<(256 * 256 + 255) / 256, 256, 0, stream>>>(W1, W1t_hi, W1t_lo,
                                                        256, 256);
  wsplit_t<<<(256 * 128 + 255) / 256, 256, 0, stream>>>(W2, W2t_hi, W2t_lo,
                                                        256, 128);
  wsplit_mv<<<(128 * 128 + 255) / 256, 256, 0, stream>>>(Wm, Wv, bm, bv,
                                                         Wmv_hi, Wmv_lo, bmv_c);
  wsplit_t<<<(64 * 256 + 255) / 256, 256, 0, stream>>>(Wd, Wdt_hi, Wdt_lo,
                                                       64, 256);

  // 0. split x -> bufA (hi | lo), 2.56M elements each
  ushort* xs_hi = (ushort*)bufA;
  ushort* xs_lo = xs_hi + (size_t)N_NODES * F_DIM;
  split_act<<<2500, 256, 0, stream>>>(x, xs_hi, xs_lo, N_NODES * F_DIM / 4);

  // 1. XW1 = x @ W1  [N, 256] -> bufB
  float* xw1 = bufB;
  gemm_mfma<false, false><<<dim3(4, (N_NODES + 63) / 64), 256, 0, stream>>>(
      xs_hi, xs_lo, W1t_hi, W1t_lo, nullptr, xw1, N_NODES, O2_DIM, F_DIM);

  // 2. h1 = relu(A_hat @ XW1 + b1) -> bufA (gather, fused bias+relu)
  float* h1 = bufA;
  gcn_gather<O2_DIM, true><<<(N_NODES + 3) / 4, 256, 0, stream>>>(
      xw1, row_start, csr_src, csr_w, b1, h1);

  // 2.5 split h1 -> bufB (XW1 dead)
  ushort* h1_hi = (ushort*)bufB;
  ushort* h1_lo = h1_hi + (size_t)N_NODES * O2_DIM;
  split_act<<<2500, 256, 0, stream>>>(h1, h1_hi, h1_lo, N_NODES * O2_DIM / 4);

  // 3. H2 = h1 @ W2  [N, 128] -> bufA first half (h1 fp32 dead)
  float* H2 = bufA;
  gemm_mfma<false, false><<<dim3(2, (N_NODES + 63) / 64), 256, 0, stream>>>(
      h1_hi, h1_lo, W2t_hi, W2t_lo, nullptr, H2, N_NODES, O_DIM, O2_DIM);

  // 4. h2 = A_hat @ H2 + b2 -> bufA second half
  float* h2 = bufA + (size_t)N_NODES * O_DIM;
  gcn_gather<O_DIM, false><<<(N_NODES + 3) / 4, 256, 0, stream>>>(
      H2, row_start, csr_src, csr_w, b2, h2);

  // 4.5 split h2 -> bufB first half (h1s dead)
  ushort* h2_hi = (ushort*)bufB;
  ushort* h2_lo = h2_hi + (size_t)N_NODES * O_DIM;
  split_act<<<1250, 256, 0, stream>>>(h2, h2_hi, h2_lo, N_NODES * O_DIM / 4);

  // 5. mv = h2 @ [Wm|Wv] + [bm|bv]  [N, 128] -> bufB second half
  float* mv = bufB + (size_t)N_NODES * O_DIM;
  gemm_mfma<true, false><<<dim3(2, (N_NODES + 63) / 64), 256, 0, stream>>>(
      h2_hi, h2_lo, Wmv_hi, Wmv_lo, bmv_c, mv, N_NODES, 128, O_DIM);

  // 6. kl = 0; fused sampler writes z (out) + zhi/zlo (bufA) + kl
  hipMemsetAsync(kl, 0, sizeof(float), stream);
  ushort* zhi = (ushort*)bufA;
  ushort* zlo = zhi + (size_t)N_NODES * L_DIM;
  sampler_fused<<<(N_NODES * L_DIM / 4 + 255) / 256, 256, 0, stream>>>(
      mv, eps, z, kl, zhi, zlo);

  // 7. feat = relu(z @ Wd + bd)  [N, 256]  (before adj: Wdt lives in adj region)
  gemm_mfma<true, true><<<dim3(4, (N_NODES + 63) / 64), 256, 0, stream>>>(
      zhi, zlo, Wdt_hi, Wdt_lo, bd, feat, N_NODES, F_DIM, L_DIM);

  // 8. adj = z @ z^T  [N, N]  (overwrites all scratch in the adj region)
  adj_mfma<<<dim3((N_NODES + 127) / 128, (N_NODES + 127) / 128), 256, 0,
             stream>>>(zhi, zlo, adj);
}

// Round 3
// 726.779 us; speedup vs baseline: 1.0982x; 1.0315x over previous
//
#include <hip/hip_runtime.h>
#include <cstddef>

// Problem constants (fixed by the reference).
#define N_NODES 10000
#define F_DIM   256
#define O2_DIM  256   // 2*O
#define O_DIM   128
#define L_DIM   64
#define E_EDGES 320000

// Output layout (flat, fp32): z | adj | feat | kl
#define Z_OFF    ((size_t)0)
#define ADJ_OFF  ((size_t)N_NODES * L_DIM)                       // 640000
#define FEAT_OFF (ADJ_OFF + (size_t)N_NODES * N_NODES)           // 100640000
#define KL_OFF   (FEAT_OFF + (size_t)N_NODES * F_DIM)            // 103200000

typedef __attribute__((ext_vector_type(8))) short short8;   // 8 bf16 (4 VGPRs)
typedef __attribute__((ext_vector_type(16))) float f32x16;  // MFMA 32x32 acc

// ---------------------------------------------------------------------------
// bf16 hi/lo split helper (RNE both stages). hi+lo reconstructs x to ~2^-24.
// ---------------------------------------------------------------------------
__device__ __forceinline__ void bsplit(float x, ushort& h, ushort& l) {
  unsigned xb = __float_as_uint(x);
  unsigned hb = (xb + 0x7fffu + ((xb >> 16) & 1u)) & 0xffff0000u;  // RNE
  h = (ushort)(hb >> 16);
  float lf = x - __uint_as_float(hb);
  unsigned lb = __float_as_uint(lf);
  l = (ushort)((lb + 0x7fffu + ((lb >> 16) & 1u)) >> 16);          // RNE
}

// ---------------------------------------------------------------------------
// Activation split: fp32 [count4*4 elements] -> bf16 hi/lo arrays.
// ---------------------------------------------------------------------------
__global__ __launch_bounds__(256) void split_act(const float* __restrict__ src,
                                                 ushort* __restrict__ hi,
                                                 ushort* __restrict__ lo,
                                                 int count4) {
  int t = blockIdx.x * 256 + threadIdx.x;
  if (t >= count4) return;
  float4 v = ((const float4*)src)[t];
  float vv[4] = {v.x, v.y, v.z, v.w};
  ushort h[4], l[4];
#pragma unroll
  for (int j = 0; j < 4; ++j) bsplit(vv[j], h[j], l[j]);
  ((ushort4*)hi)[t] = make_ushort4(h[0], h[1], h[2], h[3]);
  ((ushort4*)lo)[t] = make_ushort4(l[0], l[1], l[2], l[3]);
}

// ---------------------------------------------------------------------------
// All weight splits (transposed to [N x K]) in one dispatch. 131072 threads:
//   [0,65536)        W1 [256x256] -> W1t
//   [65536,98304)    W2 [256x128] -> W2t
//   [98304,114688)   Wm|Wv stacked -> Wmv [128x128] (+ bmv bias pack)
//   [114688,131072)  Wd [64x256]  -> Wdt [256x64]
// ---------------------------------------------------------------------------
__global__ __launch_bounds__(256) void wsplit_all(
    const float* __restrict__ W1, const float* __restrict__ W2,
    const float* __restrict__ Wm, const float* __restrict__ Wv,
    const float* __restrict__ Wd, const float* __restrict__ bm,
    const float* __restrict__ bv,
    ushort* __restrict__ W1t_hi, ushort* __restrict__ W1t_lo,
    ushort* __restrict__ W2t_hi, ushort* __restrict__ W2t_lo,
    ushort* __restrict__ Wmv_hi, ushort* __restrict__ Wmv_lo,
    ushort* __restrict__ Wdt_hi, ushort* __restrict__ Wdt_lo,
    float* __restrict__ bmv) {
  int idx = blockIdx.x * 256 + threadIdx.x;
  float v;
  ushort *ph, *pl;
  int off;
  if (idx < 65536) {
    int n = idx >> 8, k = idx & 255;
    v = W1[(size_t)k * 256 + n];
    ph = W1t_hi; pl = W1t_lo; off = idx;
  } else if (idx < 98304) {
    int j = idx - 65536;
    int n = j >> 8, k = j & 255;
    v = W2[(size_t)k * 128 + n];
    ph = W2t_hi; pl = W2t_lo; off = j;
  } else if (idx < 114688) {
    int j = idx - 98304;
    int n = j >> 7, k = j & 127;
    v = (n < 64) ? Wm[(size_t)k * 64 + n] : Wv[(size_t)k * 64 + (n - 64)];
    ph = Wmv_hi; pl = Wmv_lo; off = j;
    if (j < 128) bmv[j] = (j < 64) ? bm[j] : bv[j - 64];
  } else {
    int j = idx - 114688;
    int n = j >> 6, k = j & 63;
    v = Wd[(size_t)k * 256 + n];
    ph = Wdt_hi; pl = Wdt_lo; off = j;
  }
  ushort h, l;
  bsplit(v, h, l);
  ph[off] = h;
  pl[off] = l;
}

// ---------------------------------------------------------------------------
// Generic MFMA GEMM: C[MxNc] = A[MxK] @ B[KxNc] (+bias) (+relu), where both
// operands are pre-split bf16 hi/lo and B is pre-transposed to [Nc x K].
// All 4 cross products (hh+hl+lh+ll) -> ~fp32 accuracy.
// Tile 64x64, 4 waves in 2x2; each wave owns one 32x32 fragment.
// No LDS: operands are L2-resident; fragments load straight from global.
// A-row index clamped to M-1 (garbage confined to unstored C rows).
// Requires K % 16 == 0, Nc % 64 == 0.
// ---------------------------------------------------------------------------
template <bool BIAS, bool RELU>
__global__ __launch_bounds__(256) void gemm_mfma(
    const ushort* __restrict__ Ahi, const ushort* __restrict__ Alo,
    const ushort* __restrict__ Bhi, const ushort* __restrict__ Blo,
    const float* __restrict__ bias, float* __restrict__ C,
    int M, int Nc, int K) {
  const int tid = threadIdx.x;
  const int lane = tid & 63;
  const int w = tid >> 6;
  const int wr = w >> 1;
  const int wc = w & 1;
  const int bm0 = blockIdx.y * 64 + wr * 32;
  const int bn0 = blockIdx.x * 64 + wc * 32;
  const int rlane = lane & 31;
  const int khalf = (lane >> 5) * 8;

  int arow = bm0 + rlane;
  if (arow >= M) arow = M - 1;               // clamp: garbage rows unstored
  const size_t abase = (size_t)arow * K;
  const size_t bbase = (size_t)(bn0 + rlane) * K;   // always < Nc

  f32x16 acc;
#pragma unroll
  for (int q = 0; q < 16; ++q) acc[q] = 0.f;

  for (int ko = khalf; ko < K; ko += 16) {
    short8 ah = *(const short8*)(Ahi + abase + ko);
    short8 al = *(const short8*)(Alo + abase + ko);
    short8 bh = *(const short8*)(Bhi + bbase + ko);
    short8 bl = *(const short8*)(Blo + bbase + ko);
    acc = __builtin_amdgcn_mfma_f32_32x32x16_bf16(ah, bh, acc, 0, 0, 0);
    acc = __builtin_amdgcn_mfma_f32_32x32x16_bf16(ah, bl, acc, 0, 0, 0);
    acc = __builtin_amdgcn_mfma_f32_32x32x16_bf16(al, bh, acc, 0, 0, 0);
    acc = __builtin_amdgcn_mfma_f32_32x32x16_bf16(al, bl, acc, 0, 0, 0);
  }

  // C/D layout (measured, m74/m101): col = lane&31,
  // row = (reg&3) + 8*(reg>>2) + 4*(lane>>5).
  const int rbase = bm0 + 4 * (lane >> 5);
  const int col = bn0 + rlane;
  float bb = 0.f;
  if (BIAS) bb = bias[col];
#pragma unroll
  for (int reg = 0; reg < 16; ++reg) {
    int r = rbase + (reg & 3) + 8 * (reg >> 2);
    if (r < M) {
      float v = acc[reg] + bb;
      if (RELU) v = fmaxf(v, 0.f);
      C[(size_t)r * Nc + col] = v;
    }
  }
}

// ---------------------------------------------------------------------------
// Adjacency GEMM via MFMA: C = Z @ Z^T with Z split into bf16 hi+lo,
// C = hi*hi^T + hi*lo^T + lo*hi^T (lo*lo ~2^-18 relative: dropped).
// 128x128 tile, 4 waves 2x2, each wave a 64x64 quadrant (2x2 fragments).
// Rows clamped to N-1 (garbage confined to unstored rows/cols).
// ---------------------------------------------------------------------------
__global__ __launch_bounds__(256) void adj_mfma(const ushort* __restrict__ zhi,
                                                const ushort* __restrict__ zlo,
                                                float* __restrict__ C) {
  const int tid = threadIdx.x;
  const int lane = tid & 63;
  const int w = tid >> 6;          // wave 0..3
  const int wr = w >> 1;
  const int wc = w & 1;
  const int bm0 = blockIdx.y * 128 + wr * 64;
  const int bn0 = blockIdx.x * 128 + wc * 64;
  const int rlane = lane & 31;
  const int khalf = (lane >> 5) * 8;   // 0 or 8

  f32x16 acc[2][2];
#pragma unroll
  for (int i = 0; i < 2; ++i)
#pragma unroll
    for (int j = 0; j < 2; ++j)
#pragma unroll
      for (int q = 0; q < 16; ++q) acc[i][j][q] = 0.f;

  int ar0 = bm0 + rlane;        if (ar0 >= N_NODES) ar0 = N_NODES - 1;
  int ar1 = bm0 + 32 + rlane;   if (ar1 >= N_NODES) ar1 = N_NODES - 1;
  int br0 = bn0 + rlane;        if (br0 >= N_NODES) br0 = N_NODES - 1;
  int br1 = bn0 + 32 + rlane;   if (br1 >= N_NODES) br1 = N_NODES - 1;
  const size_t arow0 = (size_t)ar0 * L_DIM;
  const size_t arow1 = (size_t)ar1 * L_DIM;
  const size_t brow0 = (size_t)br0 * L_DIM;
  const size_t brow1 = (size_t)br1 * L_DIM;

#pragma unroll
  for (int ks = 0; ks < 4; ++ks) {
    const int ko = ks * 16 + khalf;
    short8 ah0 = *(const short8*)(zhi + arow0 + ko);
    short8 ah1 = *(const short8*)(zhi + arow1 + ko);
    short8 bh0 = *(const short8*)(zhi + brow0 + ko);
    short8 bh1 = *(const short8*)(zhi + brow1 + ko);
    short8 al0 = *(const short8*)(zlo + arow0 + ko);
    short8 al1 = *(const short8*)(zlo + arow1 + ko);
    short8 bl0 = *(const short8*)(zlo + brow0 + ko);
    short8 bl1 = *(const short8*)(zlo + brow1 + ko);

    // hi * hi
    acc[0][0] = __builtin_amdgcn_mfma_f32_32x32x16_bf16(ah0, bh0, acc[0][0], 0, 0, 0);
    acc[0][1] = __builtin_amdgcn_mfma_f32_32x32x16_bf16(ah0, bh1, acc[0][1], 0, 0, 0);
    acc[1][0] = __builtin_amdgcn_mfma_f32_32x32x16_bf16(ah1, bh0, acc[1][0], 0, 0, 0);
    acc[1][1] = __builtin_amdgcn_mfma_f32_32x32x16_bf16(ah1, bh1, acc[1][1], 0, 0, 0);
    // hi * lo
    acc[0][0] = __builtin_amdgcn_mfma_f32_32x32x16_bf16(ah0, bl0, acc[0][0], 0, 0, 0);
    acc[0][1] = __builtin_amdgcn_mfma_f32_32x32x16_bf16(ah0, bl1, acc[0][1], 0, 0, 0);
    acc[1][0] = __builtin_amdgcn_mfma_f32_32x32x16_bf16(ah1, bl0, acc[1][0], 0, 0, 0);
    acc[1][1] = __builtin_amdgcn_mfma_f32_32x32x16_bf16(ah1, bl1, acc[1][1], 0, 0, 0);
    // lo * hi
    acc[0][0] = __builtin_amdgcn_mfma_f32_32x32x16_bf16(al0, bh0, acc[0][0], 0, 0, 0);
    acc[0][1] = __builtin_amdgcn_mfma_f32_32x32x16_bf16(al0, bh1, acc[0][1], 0, 0, 0);
    acc[1][0] = __builtin_amdgcn_mfma_f32_32x32x16_bf16(al1, bh0, acc[1][0], 0, 0, 0);
    acc[1][1] = __builtin_amdgcn_mfma_f32_32x32x16_bf16(al1, bh1, acc[1][1], 0, 0, 0);
  }

#pragma unroll
  for (int ti = 0; ti < 2; ++ti) {
    const int rb = bm0 + ti * 32 + 4 * (lane >> 5);
#pragma unroll
    for (int tj = 0; tj < 2; ++tj) {
      const int col = bn0 + tj * 32 + rlane;
      if (col >= N_NODES) continue;
#pragma unroll
      for (int reg = 0; reg < 16; ++reg) {
        const int r = rb + (reg & 3) + 8 * (reg >> 2);
        if (r < N_NODES) C[(size_t)r * N_NODES + col] = acc[ti][tj][reg];
      }
    }
  }
}

// ---------------------------------------------------------------------------
// CSR build: histogram of dst, exclusive scan, cursor-based fill.
// CSR arrays live in the adj output region (written long before adj_mfma).
// ---------------------------------------------------------------------------
__global__ __launch_bounds__(256) void hist_kernel(const int* __restrict__ dst,
                                                   int* __restrict__ deg) {
  int e = blockIdx.x * blockDim.x + threadIdx.x;
  if (e < E_EDGES) atomicAdd(&deg[dst[e]], 1);
}

// Single-block exclusive scan over N_NODES degree counts.
__global__ __launch_bounds__(256) void scan_kernel(const int* __restrict__ deg,
                                                   int* __restrict__ row_start,
                                                   int* __restrict__ cursor) {
  constexpr int CH = (N_NODES + 255) / 256;  // 40
  const int t = threadIdx.x;
  __shared__ int ps[256];

  int base = t * CH;
  int sum = 0;
  for (int i = base; i < base + CH && i < N_NODES; ++i) sum += deg[i];
  ps[t] = sum;
  __syncthreads();
  for (int off = 1; off < 256; off <<= 1) {
    int v = (t >= off) ? ps[t - off] : 0;
    __syncthreads();
    ps[t] += v;
    __syncthreads();
  }
  int running = ps[t] - sum;
  for (int i = base; i < base + CH && i < N_NODES; ++i) {
    row_start[i] = running;
    cursor[i] = running;
    running += deg[i];
  }
  if (t == 255) row_start[N_NODES] = ps[255];
}

__global__ __launch_bounds__(256) void fill_kernel(
    const int* __restrict__ src, const int* __restrict__ dst,
    const float* __restrict__ ew, int* __restrict__ cursor,
    int* __restrict__ csr_src, float* __restrict__ csr_w) {
  int e = blockIdx.x * blockDim.x + threadIdx.x;
  if (e >= E_EDGES) return;
  int d = dst[e];
  int pos = atomicAdd(&cursor[d], 1);
  csr_src[pos] = src[e];
  csr_w[pos] = ew[e];
}

// ---------------------------------------------------------------------------
// Block-per-node GCN aggregation with fused bias(+relu)+bf16 hi/lo split:
//   out[n] = act( sum_{e: dst=n} w_e * H[src_e] + b )  -> hi/lo bf16 pair
// 4 waves split the node's edge list (stride 4), each batches 4 edges for
// MLP, partial sums reduced through LDS. 4x the in-flight loads per node
// vs wave-per-node, 4x less degree-tail imbalance.
// ---------------------------------------------------------------------------
template <int D, bool RELU>
__global__ __launch_bounds__(256) void gcn_gather_split(
    const float* __restrict__ H, const int* __restrict__ row_start,
    const int* __restrict__ csr_src, const float* __restrict__ csr_w,
    const float* __restrict__ bias, ushort* __restrict__ out_hi,
    ushort* __restrict__ out_lo) {
  constexpr int VEC = D / 64;  // 4 (D=256) or 2 (D=128)
  const int w = threadIdx.x >> 6;
  const int lane = threadIdx.x & 63;
  const int n = blockIdx.x;
  __shared__ float red[4][D];

  const int beg = row_start[n];
  const int end = row_start[n + 1];

  float acc[VEC] = {};
  int i = beg + w;
  for (; i + 12 < end; i += 16) {   // 4 edges: i, i+4, i+8, i+12
    int ss[4];
    float ww[4];
#pragma unroll
    for (int u = 0; u < 4; ++u) {
      ss[u] = csr_src[i + 4 * u];
      ww[u] = csr_w[i + 4 * u];
    }
    float vv[4][VEC];
#pragma unroll
    for (int u = 0; u < 4; ++u) {
      const float* rp = H + (size_t)ss[u] * D + lane * VEC;
      if constexpr (VEC == 4) {
        float4 v = *(const float4*)rp;
        vv[u][0] = v.x; vv[u][1] = v.y; vv[u][2] = v.z; vv[u][3] = v.w;
      } else {
        float2 v = *(const float2*)rp;
        vv[u][0] = v.x; vv[u][1] = v.y;
      }
    }
#pragma unroll
    for (int u = 0; u < 4; ++u)
#pragma unroll
      for (int c = 0; c < VEC; ++c) acc[c] = fmaf(vv[u][c], ww[u], acc[c]);
  }
  for (; i < end; i += 4) {
    int s = csr_src[i];
    float ww = csr_w[i];
    const float* rp = H + (size_t)s * D + lane * VEC;
    if constexpr (VEC == 4) {
      float4 v = *(const float4*)rp;
      acc[0] = fmaf(v.x, ww, acc[0]);
      acc[1] = fmaf(v.y, ww, acc[1]);
      acc[2] = fmaf(v.z, ww, acc[2]);
      acc[3] = fmaf(v.w, ww, acc[3]);
    } else {
      float2 v = *(const float2*)rp;
      acc[0] = fmaf(v.x, ww, acc[0]);
      acc[1] = fmaf(v.y, ww, acc[1]);
    }
  }

#pragma unroll
  for (int c = 0; c < VEC; ++c) red[w][lane * VEC + c] = acc[c];
  __syncthreads();

  const int t = threadIdx.x;
  if (t < D) {
    float s = red[0][t] + red[1][t] + red[2][t] + red[3][t] + bias[t];
    if (RELU) s = fmaxf(s, 0.f);
    ushort h, l;
    bsplit(s, h, l);
    out_hi[(size_t)n * D + t] = h;
    out_lo[(size_t)n * D + t] = l;
  }
}

// ---------------------------------------------------------------------------
// Fused sampler + KL + z bf16-split.
// mv layout: [node][0:64]=mean, [node][64:128]=var.
// ---------------------------------------------------------------------------
__global__ __launch_bounds__(256) void sampler_fused(
    const float* __restrict__ mv, const float* __restrict__ eps,
    float* __restrict__ z, float* __restrict__ kl,
    ushort* __restrict__ zhi, ushort* __restrict__ zlo) {
  int t = blockIdx.x * 256 + threadIdx.x;   // one float4 of z per thread
  float kls = 0.f;
  if (t < N_NODES * L_DIM / 4) {
    int node = t >> 4;
    int jq = (t & 15) << 2;
    float4 m4 = *(const float4*)(mv + (size_t)node * 128 + jq);
    float4 v4 = *(const float4*)(mv + (size_t)node * 128 + 64 + jq);
    float4 e4 = *(const float4*)(eps + (size_t)node * 64 + jq);
    float mm[4] = {m4.x, m4.y, m4.z, m4.w};
    float vv[4] = {v4.x, v4.y, v4.z, v4.w};
    float ee[4] = {e4.x, e4.y, e4.z, e4.w};
    float zf[4];
    ushort h[4], l[4];
#pragma unroll
    for (int j = 0; j < 4; ++j) {
      float m = mm[j], v = vv[j];
      float vp = fmaxf(v, 1e-7f);
      kls += 1.0f + logf(vp) - m * m - vp;
      float mc = fminf(fmaxf(m, -10.f), 10.f);
      float vc = fminf(fmaxf(v, -10.f), 10.f);
      float zz = mc + expf(0.5f * vc) * ee[j];
      zf[j] = zz;
      bsplit(zz, h[j], l[j]);
    }
    *(float4*)(z + (size_t)node * 64 + jq) =
        make_float4(zf[0], zf[1], zf[2], zf[3]);
    *(ushort4*)(zhi + (size_t)node * 64 + jq) =
        make_ushort4(h[0], h[1], h[2], h[3]);
    *(ushort4*)(zlo + (size_t)node * 64 + jq) =
        make_ushort4(l[0], l[1], l[2], l[3]);
  }
#pragma unroll
  for (int off = 32; off > 0; off >>= 1) kls += __shfl_down(kls, off, 64);
  __shared__ float wsum[4];
  if ((threadIdx.x & 63) == 0) wsum[threadIdx.x >> 6] = kls;
  __syncthreads();
  if (threadIdx.x == 0) {
    float s = wsum[0] + wsum[1] + wsum[2] + wsum[3];
    atomicAdd(kl, -0.5f * s);
  }
}

// ---------------------------------------------------------------------------
extern "C" void kernel_launch(void* const* d_in, const int* in_sizes, int n_in,
                              void* d_out, int out_size, void* d_ws,
                              size_t ws_size, hipStream_t stream) {
  const float* x  = (const float*)d_in[0];
  const int*   ei = (const int*)d_in[1];
  const float* ew = (const float*)d_in[2];
  const float* W1 = (const float*)d_in[3];
  const float* b1 = (const float*)d_in[4];
  const float* W2 = (const float*)d_in[5];
  const float* b2 = (const float*)d_in[6];
  const float* Wm = (const float*)d_in[7];
  const float* bm = (const float*)d_in[8];
  const float* Wv = (const float*)d_in[9];
  const float* bv = (const float*)d_in[10];
  const float* Wd = (const float*)d_in[11];
  const float* bd = (const float*)d_in[12];
  const float* eps = (const float*)d_in[13];

  const int* srcv = ei;             // edge_index[0]
  const int* dstv = ei + E_EDGES;   // edge_index[1]

  float* out  = (float*)d_out;
  float* z    = out + Z_OFF;
  float* adj  = out + ADJ_OFF;
  float* feat = out + FEAT_OFF;
  float* kl   = out + KL_OFF;

  // Workspace: two ping-pong buffers of N*256 floats (10.24 MB each).
  float* bufA = (float*)d_ws;
  float* bufB = bufA + (size_t)N_NODES * F_DIM;

  // Scratch in the adj output region (adj is written last):
  // CSR arrays + transposed/split weights + combined mean|var bias.
  int* deg       = (int*)adj;
  int* row_start = deg + N_NODES;          // N+1 entries
  int* cursor    = row_start + N_NODES + 1;
  int* csr_src   = cursor + N_NODES;
  float* csr_w   = (float*)(csr_src + E_EDGES);

  ushort* W1t_hi = (ushort*)(csr_w + E_EDGES);   // [256 x 256]
  ushort* W1t_lo = W1t_hi + 256 * 256;
  ushort* W2t_hi = W1t_lo + 256 * 256;           // [128 x 256]
  ushort* W2t_lo = W2t_hi + 128 * 256;
  ushort* Wmv_hi = W2t_lo + 128 * 256;           // [128 x 128] (Wm|Wv stacked)
  ushort* Wmv_lo = Wmv_hi + 128 * 128;
  ushort* Wdt_hi = Wmv_lo + 128 * 128;           // [256 x 64]
  ushort* Wdt_lo = Wdt_hi + 256 * 64;
  float*  bmv_c  = (float*)(Wdt_lo + 256 * 64);  // [128] = bm | bv

  // --- CSR build (once, reused by both convs) ---
  hipMemsetAsync(deg, 0, N_NODES * sizeof(int), stream);
  hist_kernel<<<(E_EDGES + 255) / 256, 256, 0, stream>>>(dstv, deg);
  scan_kernel<<<1, 256, 0, stream>>>(deg, row_start, cursor);
  fill_kernel<<<(E_EDGES + 255) / 256, 256, 0, stream>>>(srcv, dstv, ew, cursor,
                                                         csr_src, csr_w);

  // --- All weight splits in one dispatch ---
  wsplit_all<<<512, 256, 0, stream>>>(W1, W2, Wm, Wv, Wd, bm, bv,
                                      W1t_hi, W1t_lo, W2t_hi, W2t_lo,
                                      Wmv_hi, Wmv_lo, Wdt_hi, Wdt_lo, bmv_c);

  // 0. split x -> bufA (hi | lo)
  ushort* xs_hi = (ushort*)bufA;
  ushort* xs_lo = xs_hi + (size_t)N_NODES * F_DIM;
  split_act<<<2500, 256, 0, stream>>>(x, xs_hi, xs_lo, N_NODES * F_DIM / 4);

  // 1. XW1 = x @ W1  [N, 256] -> bufB (fp32, gather input)
  float* xw1 = bufB;
  gemm_mfma<false, false><<<dim3(4, (N_NODES + 63) / 64), 256, 0, stream>>>(
      xs_hi, xs_lo, W1t_hi, W1t_lo, nullptr, xw1, N_NODES, O2_DIM, F_DIM);

  // 2. h1 = relu(A_hat @ XW1 + b1) -> bf16 hi/lo directly in bufA
  ushort* h1_hi = (ushort*)bufA;
  ushort* h1_lo = h1_hi + (size_t)N_NODES * O2_DIM;
  gcn_gather_split<O2_DIM, true><<<N_NODES, 256, 0, stream>>>(
      xw1, row_start, csr_src, csr_w, b1, h1_hi, h1_lo);

  // 3. H2 = h1 @ W2  [N, 128] -> bufB first half (xw1 dead)
  float* H2 = bufB;
  gemm_mfma<false, false><<<dim3(2, (N_NODES + 63) / 64), 256, 0, stream>>>(
      h1_hi, h1_lo, W2t_hi, W2t_lo, nullptr, H2, N_NODES, O_DIM, O2_DIM);

  // 4. h2 = A_hat @ H2 + b2 -> bf16 hi/lo in bufB second half
  ushort* h2_hi = (ushort*)(bufB + (size_t)N_NODES * O_DIM);
  ushort* h2_lo = h2_hi + (size_t)N_NODES * O_DIM;
  gcn_gather_split<O_DIM, false><<<N_NODES, 256, 0, stream>>>(
      H2, row_start, csr_src, csr_w, b2, h2_hi, h2_lo);

  // 5. mv = h2 @ [Wm|Wv] + [bm|bv]  [N, 128] -> bufA first half (h1 splits dead)
  float* mv = bufA;
  gemm_mfma<true, false><<<dim3(2, (N_NODES + 63) / 64), 256, 0, stream>>>(
      h2_hi, h2_lo, Wmv_hi, Wmv_lo, bmv_c, mv, N_NODES, 128, O_DIM);

  // 6. kl = 0; fused sampler writes z (out) + zhi/zlo (bufA 2nd half) + kl
  hipMemsetAsync(kl, 0, sizeof(float), stream);
  ushort* zhi = (ushort*)(bufA + (size_t)N_NODES * O_DIM);
  ushort* zlo = zhi + (size_t)N_NODES * L_DIM;
  sampler_fused<<<(N_NODES * L_DIM / 4 + 255) / 256, 256, 0, stream>>>(
      mv, eps, z, kl, zhi, zlo);

  // 7. feat = relu(z @ Wd + bd)  [N, 256]  (before adj: Wdt lives in adj region)
  gemm_mfma<true, true><<<dim3(4, (N_NODES + 63) / 64), 256, 0, stream>>>(
      zhi, zlo, Wdt_hi, Wdt_lo, bd, feat, N_NODES, F_DIM, L_DIM);

  // 8. adj = z @ z^T  [N, N]  (overwrites all scratch in the adj region)
  adj_mfma<<<dim3((N_NODES + 127) / 128, (N_NODES + 127) / 128), 256, 0,
             stream>>>(zhi, zlo, adj);
}

// Round 4
// 677.368 us; speedup vs baseline: 1.1783x; 1.0729x over previous
//
#include <hip/hip_runtime.h>
#include <cstddef>

// Problem constants (fixed by the reference).
#define N_NODES 10000
#define F_DIM   256
#define O2_DIM  256   // 2*O
#define O_DIM   128
#define L_DIM   64
#define E_EDGES 320000

// Output layout (flat, fp32): z | adj | feat | kl
#define Z_OFF    ((size_t)0)
#define ADJ_OFF  ((size_t)N_NODES * L_DIM)                       // 640000
#define FEAT_OFF (ADJ_OFF + (size_t)N_NODES * N_NODES)           // 100640000
#define KL_OFF   (FEAT_OFF + (size_t)N_NODES * F_DIM)            // 103200000

typedef __attribute__((ext_vector_type(8))) short short8;   // 8 bf16 (4 VGPRs)
typedef __attribute__((ext_vector_type(16))) float f32x16;  // MFMA 32x32 acc

// ---------------------------------------------------------------------------
// bf16 hi/lo split helper (RNE both stages). hi+lo reconstructs x to ~2^-24.
// ---------------------------------------------------------------------------
__device__ __forceinline__ void bsplit(float x, ushort& h, ushort& l) {
  unsigned xb = __float_as_uint(x);
  unsigned hb = (xb + 0x7fffu + ((xb >> 16) & 1u)) & 0xffff0000u;  // RNE
  h = (ushort)(hb >> 16);
  float lf = x - __uint_as_float(hb);
  unsigned lb = __float_as_uint(lf);
  l = (ushort)((lb + 0x7fffu + ((lb >> 16) & 1u)) >> 16);          // RNE
}

// ---------------------------------------------------------------------------
// One-shot prep kernel (replaces 2 memsets + weight-split + x-split):
//   blocks [0,512)      : all weight splits (transposed to [N x K])
//   blocks [512,3012)   : x [10000x256] fp32 -> bf16 hi/lo
//   block  3012         : zero deg[10000] and kl
// ---------------------------------------------------------------------------
__global__ __launch_bounds__(256) void prep_all(
    const float* __restrict__ x, const float* __restrict__ W1,
    const float* __restrict__ W2, const float* __restrict__ Wm,
    const float* __restrict__ Wv, const float* __restrict__ Wd,
    const float* __restrict__ bm, const float* __restrict__ bv,
    ushort* __restrict__ xs_hi, ushort* __restrict__ xs_lo,
    ushort* __restrict__ W1t_hi, ushort* __restrict__ W1t_lo,
    ushort* __restrict__ W2t_hi, ushort* __restrict__ W2t_lo,
    ushort* __restrict__ Wmv_hi, ushort* __restrict__ Wmv_lo,
    ushort* __restrict__ Wdt_hi, ushort* __restrict__ Wdt_lo,
    float* __restrict__ bmv, int* __restrict__ deg, float* __restrict__ kl) {
  const int b = blockIdx.x;
  if (b >= 3012) {  // housekeeping block
    for (int i = threadIdx.x; i < N_NODES; i += 256) deg[i] = 0;
    if (threadIdx.x == 0) *kl = 0.f;
    return;
  }
  if (b >= 512) {   // x split: one float4 per thread
    int t = (b - 512) * 256 + threadIdx.x;   // < 640000 exactly
    float4 v = ((const float4*)x)[t];
    float vv[4] = {v.x, v.y, v.z, v.w};
    ushort h[4], l[4];
#pragma unroll
    for (int j = 0; j < 4; ++j) bsplit(vv[j], h[j], l[j]);
    ((ushort4*)xs_hi)[t] = make_ushort4(h[0], h[1], h[2], h[3]);
    ((ushort4*)xs_lo)[t] = make_ushort4(l[0], l[1], l[2], l[3]);
    return;
  }
  // weight splits, 131072 threads
  int idx = b * 256 + threadIdx.x;
  float v;
  ushort *ph, *pl;
  int off;
  if (idx < 65536) {
    int n = idx >> 8, k = idx & 255;
    v = W1[(size_t)k * 256 + n];
    ph = W1t_hi; pl = W1t_lo; off = idx;
  } else if (idx < 98304) {
    int j = idx - 65536;
    int n = j >> 8, k = j & 255;
    v = W2[(size_t)k * 128 + n];
    ph = W2t_hi; pl = W2t_lo; off = j;
  } else if (idx < 114688) {
    int j = idx - 98304;
    int n = j >> 7, k = j & 127;
    v = (n < 64) ? Wm[(size_t)k * 64 + n] : Wv[(size_t)k * 64 + (n - 64)];
    ph = Wmv_hi; pl = Wmv_lo; off = j;
    if (j < 128) bmv[j] = (j < 64) ? bm[j] : bv[j - 64];
  } else {
    int j = idx - 114688;
    int n = j >> 6, k = j & 63;
    v = Wd[(size_t)k * 256 + n];
    ph = Wdt_hi; pl = Wdt_lo; off = j;
  }
  ushort h, l;
  bsplit(v, h, l);
  ph[off] = h;
  pl[off] = l;
}

// ---------------------------------------------------------------------------
// Generic MFMA GEMM: C[MxNc] = A[MxK] @ B[KxNc] (+bias) (+relu), where both
// operands are pre-split bf16 hi/lo and B is pre-transposed to [Nc x K].
// All 4 cross products (hh+hl+lh+ll) -> ~fp32 accuracy.
// Tile 64x64, 4 waves in 2x2; each wave owns one 32x32 fragment.
// No LDS: operands are L2-resident; fragments load straight from global.
// NT: non-temporal C stores (output never re-read on device).
// ---------------------------------------------------------------------------
template <bool BIAS, bool RELU, bool NT>
__global__ __launch_bounds__(256) void gemm_mfma(
    const ushort* __restrict__ Ahi, const ushort* __restrict__ Alo,
    const ushort* __restrict__ Bhi, const ushort* __restrict__ Blo,
    const float* __restrict__ bias, float* __restrict__ C,
    int M, int Nc, int K) {
  const int tid = threadIdx.x;
  const int lane = tid & 63;
  const int w = tid >> 6;
  const int wr = w >> 1;
  const int wc = w & 1;
  const int bm0 = blockIdx.y * 64 + wr * 32;
  const int bn0 = blockIdx.x * 64 + wc * 32;
  const int rlane = lane & 31;
  const int khalf = (lane >> 5) * 8;

  int arow = bm0 + rlane;
  if (arow >= M) arow = M - 1;               // clamp: garbage rows unstored
  const size_t abase = (size_t)arow * K;
  const size_t bbase = (size_t)(bn0 + rlane) * K;   // always < Nc

  f32x16 acc;
#pragma unroll
  for (int q = 0; q < 16; ++q) acc[q] = 0.f;

  for (int ko = khalf; ko < K; ko += 16) {
    short8 ah = *(const short8*)(Ahi + abase + ko);
    short8 al = *(const short8*)(Alo + abase + ko);
    short8 bh = *(const short8*)(Bhi + bbase + ko);
    short8 bl = *(const short8*)(Blo + bbase + ko);
    acc = __builtin_amdgcn_mfma_f32_32x32x16_bf16(ah, bh, acc, 0, 0, 0);
    acc = __builtin_amdgcn_mfma_f32_32x32x16_bf16(ah, bl, acc, 0, 0, 0);
    acc = __builtin_amdgcn_mfma_f32_32x32x16_bf16(al, bh, acc, 0, 0, 0);
    acc = __builtin_amdgcn_mfma_f32_32x32x16_bf16(al, bl, acc, 0, 0, 0);
  }

  // C/D layout (measured, m74/m101): col = lane&31,
  // row = (reg&3) + 8*(reg>>2) + 4*(lane>>5).
  const int rbase = bm0 + 4 * (lane >> 5);
  const int col = bn0 + rlane;
  float bb = 0.f;
  if (BIAS) bb = bias[col];
#pragma unroll
  for (int reg = 0; reg < 16; ++reg) {
    int r = rbase + (reg & 3) + 8 * (reg >> 2);
    if (r < M) {
      float v = acc[reg] + bb;
      if (RELU) v = fmaxf(v, 0.f);
      float* p = C + (size_t)r * Nc + col;
      if (NT) __builtin_nontemporal_store(v, p);
      else *p = v;
    }
  }
}

// ---------------------------------------------------------------------------
// Adjacency GEMM via MFMA: C = Z @ Z^T with Z split into bf16 hi+lo,
// C = hi*hi^T + hi*lo^T + lo*hi^T (lo*lo ~2^-18 relative: dropped).
// 128x128 tile, 4 waves 2x2, each wave a 64x64 quadrant (2x2 fragments).
// Rows clamped to N-1 (garbage confined to unstored rows/cols).
// Non-temporal stores: adj (400 MB) is never re-read on device.
// ---------------------------------------------------------------------------
__global__ __launch_bounds__(256) void adj_mfma(const ushort* __restrict__ zhi,
                                                const ushort* __restrict__ zlo,
                                                float* __restrict__ C) {
  const int tid = threadIdx.x;
  const int lane = tid & 63;
  const int w = tid >> 6;          // wave 0..3
  const int wr = w >> 1;
  const int wc = w & 1;
  const int bm0 = blockIdx.y * 128 + wr * 64;
  const int bn0 = blockIdx.x * 128 + wc * 64;
  const int rlane = lane & 31;
  const int khalf = (lane >> 5) * 8;   // 0 or 8

  f32x16 acc[2][2];
#pragma unroll
  for (int i = 0; i < 2; ++i)
#pragma unroll
    for (int j = 0; j < 2; ++j)
#pragma unroll
      for (int q = 0; q < 16; ++q) acc[i][j][q] = 0.f;

  int ar0 = bm0 + rlane;        if (ar0 >= N_NODES) ar0 = N_NODES - 1;
  int ar1 = bm0 + 32 + rlane;   if (ar1 >= N_NODES) ar1 = N_NODES - 1;
  int br0 = bn0 + rlane;        if (br0 >= N_NODES) br0 = N_NODES - 1;
  int br1 = bn0 + 32 + rlane;   if (br1 >= N_NODES) br1 = N_NODES - 1;
  const size_t arow0 = (size_t)ar0 * L_DIM;
  const size_t arow1 = (size_t)ar1 * L_DIM;
  const size_t brow0 = (size_t)br0 * L_DIM;
  const size_t brow1 = (size_t)br1 * L_DIM;

#pragma unroll
  for (int ks = 0; ks < 4; ++ks) {
    const int ko = ks * 16 + khalf;
    short8 ah0 = *(const short8*)(zhi + arow0 + ko);
    short8 ah1 = *(const short8*)(zhi + arow1 + ko);
    short8 bh0 = *(const short8*)(zhi + brow0 + ko);
    short8 bh1 = *(const short8*)(zhi + brow1 + ko);
    short8 al0 = *(const short8*)(zlo + arow0 + ko);
    short8 al1 = *(const short8*)(zlo + arow1 + ko);
    short8 bl0 = *(const short8*)(zlo + brow0 + ko);
    short8 bl1 = *(const short8*)(zlo + brow1 + ko);

    // hi * hi
    acc[0][0] = __builtin_amdgcn_mfma_f32_32x32x16_bf16(ah0, bh0, acc[0][0], 0, 0, 0);
    acc[0][1] = __builtin_amdgcn_mfma_f32_32x32x16_bf16(ah0, bh1, acc[0][1], 0, 0, 0);
    acc[1][0] = __builtin_amdgcn_mfma_f32_32x32x16_bf16(ah1, bh0, acc[1][0], 0, 0, 0);
    acc[1][1] = __builtin_amdgcn_mfma_f32_32x32x16_bf16(ah1, bh1, acc[1][1], 0, 0, 0);
    // hi * lo
    acc[0][0] = __builtin_amdgcn_mfma_f32_32x32x16_bf16(ah0, bl0, acc[0][0], 0, 0, 0);
    acc[0][1] = __builtin_amdgcn_mfma_f32_32x32x16_bf16(ah0, bl1, acc[0][1], 0, 0, 0);
    acc[1][0] = __builtin_amdgcn_mfma_f32_32x32x16_bf16(ah1, bl0, acc[1][0], 0, 0, 0);
    acc[1][1] = __builtin_amdgcn_mfma_f32_32x32x16_bf16(ah1, bl1, acc[1][1], 0, 0, 0);
    // lo * hi
    acc[0][0] = __builtin_amdgcn_mfma_f32_32x32x16_bf16(al0, bh0, acc[0][0], 0, 0, 0);
    acc[0][1] = __builtin_amdgcn_mfma_f32_32x32x16_bf16(al0, bh1, acc[0][1], 0, 0, 0);
    acc[1][0] = __builtin_amdgcn_mfma_f32_32x32x16_bf16(al1, bh0, acc[1][0], 0, 0, 0);
    acc[1][1] = __builtin_amdgcn_mfma_f32_32x32x16_bf16(al1, bh1, acc[1][1], 0, 0, 0);
  }

#pragma unroll
  for (int ti = 0; ti < 2; ++ti) {
    const int rb = bm0 + ti * 32 + 4 * (lane >> 5);
#pragma unroll
    for (int tj = 0; tj < 2; ++tj) {
      const int col = bn0 + tj * 32 + rlane;
      if (col >= N_NODES) continue;
#pragma unroll
      for (int reg = 0; reg < 16; ++reg) {
        const int r = rb + (reg & 3) + 8 * (reg >> 2);
        if (r < N_NODES)
          __builtin_nontemporal_store(acc[ti][tj][reg],
                                      C + (size_t)r * N_NODES + col);
      }
    }
  }
}

// ---------------------------------------------------------------------------
// CSR build: histogram of dst, exclusive scan, cursor-based fill.
// CSR arrays live in the adj output region (written long before adj_mfma).
// ---------------------------------------------------------------------------
__global__ __launch_bounds__(256) void hist_kernel(const int* __restrict__ dst,
                                                   int* __restrict__ deg) {
  int e = blockIdx.x * blockDim.x + threadIdx.x;
  if (e < E_EDGES) atomicAdd(&deg[dst[e]], 1);
}

// Single-block exclusive scan over N_NODES degree counts.
__global__ __launch_bounds__(256) void scan_kernel(const int* __restrict__ deg,
                                                   int* __restrict__ row_start,
                                                   int* __restrict__ cursor) {
  constexpr int CH = (N_NODES + 255) / 256;  // 40
  const int t = threadIdx.x;
  __shared__ int ps[256];

  int base = t * CH;
  int sum = 0;
  for (int i = base; i < base + CH && i < N_NODES; ++i) sum += deg[i];
  ps[t] = sum;
  __syncthreads();
  for (int off = 1; off < 256; off <<= 1) {
    int v = (t >= off) ? ps[t - off] : 0;
    __syncthreads();
    ps[t] += v;
    __syncthreads();
  }
  int running = ps[t] - sum;
  for (int i = base; i < base + CH && i < N_NODES; ++i) {
    row_start[i] = running;
    cursor[i] = running;
    running += deg[i];
  }
  if (t == 255) row_start[N_NODES] = ps[255];
}

__global__ __launch_bounds__(256) void fill_kernel(
    const int* __restrict__ src, const int* __restrict__ dst,
    const float* __restrict__ ew, int* __restrict__ cursor,
    int* __restrict__ csr_src, float* __restrict__ csr_w) {
  int e = blockIdx.x * blockDim.x + threadIdx.x;
  if (e >= E_EDGES) return;
  int d = dst[e];
  int pos = atomicAdd(&cursor[d], 1);
  csr_src[pos] = src[e];
  csr_w[pos] = ew[e];
}

// ---------------------------------------------------------------------------
// Block-per-node GCN aggregation with fused bias(+relu)+bf16 hi/lo split:
//   out[n] = act( sum_{e: dst=n} w_e * H[src_e] + b )  -> hi/lo bf16 pair
// 4 waves split the node's edge list (stride 4). Edges batched 8-deep
// (a wave's typical 8 edges at deg~32 issue all row loads concurrently),
// then 4-deep, then singles. Partials reduced through LDS.
// ---------------------------------------------------------------------------
template <int D, bool RELU>
__global__ __launch_bounds__(256) void gcn_gather_split(
    const float* __restrict__ H, const int* __restrict__ row_start,
    const int* __restrict__ csr_src, const float* __restrict__ csr_w,
    const float* __restrict__ bias, ushort* __restrict__ out_hi,
    ushort* __restrict__ out_lo) {
  constexpr int VEC = D / 64;  // 4 (D=256) or 2 (D=128)
  const int w = threadIdx.x >> 6;
  const int lane = threadIdx.x & 63;
  const int n = blockIdx.x;
  __shared__ float red[4][D];

  const int beg = row_start[n];
  const int end = row_start[n + 1];

  float acc[VEC] = {};
  int i = beg + w;
  // 8-edge batches (wave-stride 4 between edges)
  for (; i + 28 < end; i += 32) {
    int ss[8];
    float ww[8];
#pragma unroll
    for (int u = 0; u < 8; ++u) {
      ss[u] = csr_src[i + 4 * u];
      ww[u] = csr_w[i + 4 * u];
    }
    float vv[8][VEC];
#pragma unroll
    for (int u = 0; u < 8; ++u) {
      const float* rp = H + (size_t)ss[u] * D + lane * VEC;
      if constexpr (VEC == 4) {
        float4 v = *(const float4*)rp;
        vv[u][0] = v.x; vv[u][1] = v.y; vv[u][2] = v.z; vv[u][3] = v.w;
      } else {
        float2 v = *(const float2*)rp;
        vv[u][0] = v.x; vv[u][1] = v.y;
      }
    }
#pragma unroll
    for (int u = 0; u < 8; ++u)
#pragma unroll
      for (int c = 0; c < VEC; ++c) acc[c] = fmaf(vv[u][c], ww[u], acc[c]);
  }
  // 4-edge batch
  for (; i + 12 < end; i += 16) {
    int ss[4];
    float ww[4];
#pragma unroll
    for (int u = 0; u < 4; ++u) {
      ss[u] = csr_src[i + 4 * u];
      ww[u] = csr_w[i + 4 * u];
    }
    float vv[4][VEC];
#pragma unroll
    for (int u = 0; u < 4; ++u) {
      const float* rp = H + (size_t)ss[u] * D + lane * VEC;
      if constexpr (VEC == 4) {
        float4 v = *(const float4*)rp;
        vv[u][0] = v.x; vv[u][1] = v.y; vv[u][2] = v.z; vv[u][3] = v.w;
      } else {
        float2 v = *(const float2*)rp;
        vv[u][0] = v.x; vv[u][1] = v.y;
      }
    }
#pragma unroll
    for (int u = 0; u < 4; ++u)
#pragma unroll
      for (int c = 0; c < VEC; ++c) acc[c] = fmaf(vv[u][c], ww[u], acc[c]);
  }
  // singles
  for (; i < end; i += 4) {
    int s = csr_src[i];
    float ww = csr_w[i];
    const float* rp = H + (size_t)s * D + lane * VEC;
    if constexpr (VEC == 4) {
      float4 v = *(const float4*)rp;
      acc[0] = fmaf(v.x, ww, acc[0]);
      acc[1] = fmaf(v.y, ww, acc[1]);
      acc[2] = fmaf(v.z, ww, acc[2]);
      acc[3] = fmaf(v.w, ww, acc[3]);
    } else {
      float2 v = *(const float2*)rp;
      acc[0] = fmaf(v.x, ww, acc[0]);
      acc[1] = fmaf(v.y, ww, acc[1]);
    }
  }

#pragma unroll
  for (int c = 0; c < VEC; ++c) red[w][lane * VEC + c] = acc[c];
  __syncthreads();

  const int t = threadIdx.x;
  if (t < D) {
    float s = red[0][t] + red[1][t] + red[2][t] + red[3][t] + bias[t];
    if (RELU) s = fmaxf(s, 0.f);
    ushort h, l;
    bsplit(s, h, l);
    out_hi[(size_t)n * D + t] = h;
    out_lo[(size_t)n * D + t] = l;
  }
}

// ---------------------------------------------------------------------------
// Fused sampler + KL + z bf16-split.
// mv layout: [node][0:64]=mean, [node][64:128]=var.
// ---------------------------------------------------------------------------
__global__ __launch_bounds__(256) void sampler_fused(
    const float* __restrict__ mv, const float* __restrict__ eps,
    float* __restrict__ z, float* __restrict__ kl,
    ushort* __restrict__ zhi, ushort* __restrict__ zlo) {
  int t = blockIdx.x * 256 + threadIdx.x;   // one float4 of z per thread
  float kls = 0.f;
  if (t < N_NODES * L_DIM / 4) {
    int node = t >> 4;
    int jq = (t & 15) << 2;
    float4 m4 = *(const float4*)(mv + (size_t)node * 128 + jq);
    float4 v4 = *(const float4*)(mv + (size_t)node * 128 + 64 + jq);
    float4 e4 = *(const float4*)(eps + (size_t)node * 64 + jq);
    float mm[4] = {m4.x, m4.y, m4.z, m4.w};
    float vv[4] = {v4.x, v4.y, v4.z, v4.w};
    float ee[4] = {e4.x, e4.y, e4.z, e4.w};
    float zf[4];
    ushort h[4], l[4];
#pragma unroll
    for (int j = 0; j < 4; ++j) {
      float m = mm[j], v = vv[j];
      float vp = fmaxf(v, 1e-7f);
      kls += 1.0f + logf(vp) - m * m - vp;
      float mc = fminf(fmaxf(m, -10.f), 10.f);
      float vc = fminf(fmaxf(v, -10.f), 10.f);
      float zz = mc + expf(0.5f * vc) * ee[j];
      zf[j] = zz;
      bsplit(zz, h[j], l[j]);
    }
    *(float4*)(z + (size_t)node * 64 + jq) =
        make_float4(zf[0], zf[1], zf[2], zf[3]);
    *(ushort4*)(zhi + (size_t)node * 64 + jq) =
        make_ushort4(h[0], h[1], h[2], h[3]);
    *(ushort4*)(zlo + (size_t)node * 64 + jq) =
        make_ushort4(l[0], l[1], l[2], l[3]);
  }
#pragma unroll
  for (int off = 32; off > 0; off >>= 1) kls += __shfl_down(kls, off, 64);
  __shared__ float wsum[4];
  if ((threadIdx.x & 63) == 0) wsum[threadIdx.x >> 6] = kls;
  __syncthreads();
  if (threadIdx.x == 0) {
    float s = wsum[0] + wsum[1] + wsum[2] + wsum[3];
    atomicAdd(kl, -0.5f * s);
  }
}

// ---------------------------------------------------------------------------
extern "C" void kernel_launch(void* const* d_in, const int* in_sizes, int n_in,
                              void* d_out, int out_size, void* d_ws,
                              size_t ws_size, hipStream_t stream) {
  const float* x  = (const float*)d_in[0];
  const int*   ei = (const int*)d_in[1];
  const float* ew = (const float*)d_in[2];
  const float* W1 = (const float*)d_in[3];
  const float* b1 = (const float*)d_in[4];
  const float* W2 = (const float*)d_in[5];
  const float* b2 = (const float*)d_in[6];
  const float* Wm = (const float*)d_in[7];
  const float* bm = (const float*)d_in[8];
  const float* Wv = (const float*)d_in[9];
  const float* bv = (const float*)d_in[10];
  const float* Wd = (const float*)d_in[11];
  const float* bd = (const float*)d_in[12];
  const float* eps = (const float*)d_in[13];

  const int* srcv = ei;             // edge_index[0]
  const int* dstv = ei + E_EDGES;   // edge_index[1]

  float* out  = (float*)d_out;
  float* z    = out + Z_OFF;
  float* adj  = out + ADJ_OFF;
  float* feat = out + FEAT_OFF;
  float* kl   = out + KL_OFF;

  // Workspace: two ping-pong buffers of N*256 floats (10.24 MB each).
  float* bufA = (float*)d_ws;
  float* bufB = bufA + (size_t)N_NODES * F_DIM;

  // Scratch in the adj output region (adj is written last):
  // CSR arrays + transposed/split weights + combined mean|var bias.
  int* deg       = (int*)adj;
  int* row_start = deg + N_NODES;          // N+1 entries
  int* cursor    = row_start + N_NODES + 1;
  int* csr_src   = cursor + N_NODES;
  float* csr_w   = (float*)(csr_src + E_EDGES);

  ushort* W1t_hi = (ushort*)(csr_w + E_EDGES);   // [256 x 256]
  ushort* W1t_lo = W1t_hi + 256 * 256;
  ushort* W2t_hi = W1t_lo + 256 * 256;           // [128 x 256]
  ushort* W2t_lo = W2t_hi + 128 * 256;
  ushort* Wmv_hi = W2t_lo + 128 * 256;           // [128 x 128] (Wm|Wv stacked)
  ushort* Wmv_lo = Wmv_hi + 128 * 128;
  ushort* Wdt_hi = Wmv_lo + 128 * 128;           // [256 x 64]
  ushort* Wdt_lo = Wdt_hi + 256 * 64;
  float*  bmv_c  = (float*)(Wdt_lo + 256 * 64);  // [128] = bm | bv

  // 0. prep: weight splits + x split + zero deg/kl — one dispatch
  ushort* xs_hi = (ushort*)bufA;
  ushort* xs_lo = xs_hi + (size_t)N_NODES * F_DIM;
  prep_all<<<3013, 256, 0, stream>>>(x, W1, W2, Wm, Wv, Wd, bm, bv,
                                     xs_hi, xs_lo, W1t_hi, W1t_lo,
                                     W2t_hi, W2t_lo, Wmv_hi, Wmv_lo,
                                     Wdt_hi, Wdt_lo, bmv_c, deg, kl);

  // --- CSR build (once, reused by both convs) ---
  hist_kernel<<<(E_EDGES + 255) / 256, 256, 0, stream>>>(dstv, deg);
  scan_kernel<<<1, 256, 0, stream>>>(deg, row_start, cursor);
  fill_kernel<<<(E_EDGES + 255) / 256, 256, 0, stream>>>(srcv, dstv, ew, cursor,
                                                         csr_src, csr_w);

  // 1. XW1 = x @ W1  [N, 256] -> bufB (fp32, gather input)
  float* xw1 = bufB;
  gemm_mfma<false, false, false><<<dim3(4, (N_NODES + 63) / 64), 256, 0,
                                   stream>>>(xs_hi, xs_lo, W1t_hi, W1t_lo,
                                             nullptr, xw1, N_NODES, O2_DIM,
                                             F_DIM);

  // 2. h1 = relu(A_hat @ XW1 + b1) -> bf16 hi/lo directly in bufA
  ushort* h1_hi = (ushort*)bufA;
  ushort* h1_lo = h1_hi + (size_t)N_NODES * O2_DIM;
  gcn_gather_split<O2_DIM, true><<<N_NODES, 256, 0, stream>>>(
      xw1, row_start, csr_src, csr_w, b1, h1_hi, h1_lo);

  // 3. H2 = h1 @ W2  [N, 128] -> bufB first half (xw1 dead)
  float* H2 = bufB;
  gemm_mfma<false, false, false><<<dim3(2, (N_NODES + 63) / 64), 256, 0,
                                   stream>>>(h1_hi, h1_lo, W2t_hi, W2t_lo,
                                             nullptr, H2, N_NODES, O_DIM,
                                             O2_DIM);

  // 4. h2 = A_hat @ H2 + b2 -> bf16 hi/lo in bufB second half
  ushort* h2_hi = (ushort*)(bufB + (size_t)N_NODES * O_DIM);
  ushort* h2_lo = h2_hi + (size_t)N_NODES * O_DIM;
  gcn_gather_split<O_DIM, false><<<N_NODES, 256, 0, stream>>>(
      H2, row_start, csr_src, csr_w, b2, h2_hi, h2_lo);

  // 5. mv = h2 @ [Wm|Wv] + [bm|bv]  [N, 128] -> bufA first half
  float* mv = bufA;
  gemm_mfma<true, false, false><<<dim3(2, (N_NODES + 63) / 64), 256, 0,
                                  stream>>>(h2_hi, h2_lo, Wmv_hi, Wmv_lo,
                                            bmv_c, mv, N_NODES, 128, O_DIM);

  // 6. fused sampler writes z (out) + zhi/zlo (bufA 2nd half) + kl
  ushort* zhi = (ushort*)(bufA + (size_t)N_NODES * O_DIM);
  ushort* zlo = zhi + (size_t)N_NODES * L_DIM;
  sampler_fused<<<(N_NODES * L_DIM / 4 + 255) / 256, 256, 0, stream>>>(
      mv, eps, z, kl, zhi, zlo);

  // 7. feat = relu(z @ Wd + bd)  [N, 256]  (before adj: Wdt lives in adj region)
  gemm_mfma<true, true, true><<<dim3(4, (N_NODES + 63) / 64), 256, 0, stream>>>(
      zhi, zlo, Wdt_hi, Wdt_lo, bd, feat, N_NODES, F_DIM, L_DIM);

  // 8. adj = z @ z^T  [N, N]  (overwrites all scratch in the adj region)
  adj_mfma<<<dim3((N_NODES + 127) / 128, (N_NODES + 127) / 128), 256, 0,
             stream>>>(zhi, zlo, adj);
}